// Round 23
// baseline (273.434 us; speedup 1.0000x reference)
//
#include <hip/hip_runtime.h>
#include <hip/hip_fp8.h>
#include <math.h>

#define H 128
#define DXI 8
#define NNODES 100000
#define NEDGES 1000000
#define NRUNS (NEDGES / 64)
#define NDOM 32768
#define NBND 8192
#define NPTS (NDOM + NBND)
#define INV_RE 1.45e-05f
#define NODE_BLOCKS 1024
#define NPR (NNODES / 8)        // dst range size per partition = 12500
#define RCAP 131072             // per-range epack capacity (125K avg + slack)

#define NSB ((NNODES + 1023) / 1024)   // scan blocks (1024 elems each) = 98

// d_out layout (floats): out_sup[300000] | continuity[32768] | momx[32768] | momy[32768] | boundary[8192]
#define CONT_OFF (NNODES * 3)
#define MOMX_OFF (CONT_OFF + NDOM)
#define MOMY_OFF (MOMX_OFF + NDOM)
#define BND_OFF  (MOMY_OFF + NDOM)

#define KPAD 136                 // halves per LDS row (128 + 8 pad -> 272B, 16B mult)
#define A_STRIDE (32 * KPAD)     // halves per A matrix

typedef __attribute__((ext_vector_type(8))) short short8;
typedef __attribute__((ext_vector_type(4))) float f32x4;

// fast tanh: 1 - 2/(exp2(2x*log2e)+1). Saturates correctly at +/-inf.
__device__ __forceinline__ float fast_tanh(float x) {
    const float e = __builtin_amdgcn_exp2f(x * 2.88539008f);
    return fmaf(-2.f, __builtin_amdgcn_rcpf(e + 1.f), 1.f);
}

// pack two floats to bf16 pair (RNE), low word = a, high word = b
__device__ __forceinline__ unsigned pack_bf16(float a, float b) {
    unsigned ua = __float_as_uint(a), ub = __float_as_uint(b);
    ua += 0x7fffu + ((ua >> 16) & 1u);
    ub += 0x7fffu + ((ub >> 16) & 1u);
    return (ua >> 16) | (ub & 0xffff0000u);
}

__device__ __forceinline__ short to_bf16(float f) {
    unsigned u = __float_as_uint(f);
    u += 0x7fffu + ((u >> 16) & 1u);
    return (short)(u >> 16);
}

__device__ __forceinline__ float fp8_dec(unsigned b) {
    __hip_fp8_e4m3 d;
    d.__x = (__hip_fp8_storage_t)b;
    return (float)d;
}

// ---------------------------------------------------------------------------
// Pass 1: bucket + histogram. One sequential sweep of dst/eidx/eattr.
// Per 256-edge batch: LDS-count the 8 dst-ranges, reserve contiguous space
// via 8 global atomics, write packed 8B records compactly into per-range
// arrays (coalesced chunks). Histogram atomic folded in.
// Record: 58-bit pack {src:17 | dst:17 | fp8 e0,e1,e3} in uint2.
// ---------------------------------------------------------------------------
__global__ __launch_bounds__(256) void bucket_hist_kernel(
    const int* __restrict__ eidx, const float* __restrict__ eattr,
    int* __restrict__ counts, int* __restrict__ gcur, uint2* __restrict__ epack)
{
    __shared__ int lcnt[8];
    __shared__ int lbase[8];
    const int* dst = eidx + NEDGES;
    const int CH = 1024;
    const int ebeg = blockIdx.x * CH;
#pragma unroll
    for (int it = 0; it < CH / 256; ++it) {
        const int e = ebeg + it * 256 + threadIdx.x;
        if (threadIdx.x < 8) lcnt[threadIdx.x] = 0;
        __syncthreads();
        int r = -1, myoff = 0;
        uint2 v = make_uint2(0u, 0u);
        if (e < NEDGES) {
            const int d = dst[e];
            atomicAdd(&counts[d], 1);
            const float4 ea = ((const float4*)eattr)[e];
            const __hip_fp8_e4m3 f0(ea.x), f1(ea.y), f3(ea.w);
            const unsigned long long pv =
                (unsigned long long)(unsigned)eidx[e]
              | ((unsigned long long)(unsigned)d << 17)
              | ((unsigned long long)f0.__x << 34)
              | ((unsigned long long)f1.__x << 42)
              | ((unsigned long long)f3.__x << 50);
            v = make_uint2((unsigned)pv, (unsigned)(pv >> 32));
            r = d / NPR;
            myoff = atomicAdd(&lcnt[r], 1);
        }
        __syncthreads();
        if (threadIdx.x < 8)
            lbase[threadIdx.x] = atomicAdd(&gcur[threadIdx.x], lcnt[threadIdx.x]);
        __syncthreads();
        if (r >= 0)
            epack[(size_t)r * RCAP + lbase[r] + myoff] = v;
        __syncthreads();
    }
}

// ---------------------------------------------------------------------------
// CSR scan pass 1 + th table (fp8) + agg zero-init. Grid 2048: blocks
// < NSB run the exclusive scan; ALL blocks stream th/agg work.
// ---------------------------------------------------------------------------
__global__ __launch_bounds__(256) void scan1_kernel(
    const int* __restrict__ counts, int* __restrict__ excl, int* __restrict__ bsum,
    const float* __restrict__ x, const float* __restrict__ pos,
    const float* __restrict__ Wx, const float* __restrict__ Wp,
    unsigned short* __restrict__ th, uint4* __restrict__ agg4)
{
    const int tid = threadIdx.x;

    if (blockIdx.x < NSB) {
        const int b = blockIdx.x;
        const int base = b * 1024 + tid * 4;
        int v0 = 0, v1 = 0, v2 = 0, v3 = 0;
        if (base + 3 < NNODES) {
            const int4 t = *(const int4*)(counts + base);
            v0 = t.x; v1 = t.y; v2 = t.z; v3 = t.w;
        } else {
            if (base     < NNODES) v0 = counts[base];
            if (base + 1 < NNODES) v1 = counts[base + 1];
            if (base + 2 < NNODES) v2 = counts[base + 2];
            if (base + 3 < NNODES) v3 = counts[base + 3];
        }
        const int own = v0 + v1 + v2 + v3;
        int s = own;
        const int lane = tid & 63, wv = tid >> 6;
#pragma unroll
        for (int d = 1; d < 64; d <<= 1) {
            const int t = __shfl_up(s, d);
            if (lane >= d) s += t;
        }
        __shared__ int wsum[4];
        if (lane == 63) wsum[wv] = s;
        __syncthreads();
        int woff = 0;
        for (int w = 0; w < wv; ++w) woff += wsum[w];
        const int e0 = s - own + woff;
        const int e1 = e0 + v0, e2 = e1 + v1, e3 = e2 + v2;
        if (base + 3 < NNODES) {
            *(int4*)(excl + base) = make_int4(e0, e1, e2, e3);
        } else {
            if (base     < NNODES) excl[base]     = e0;
            if (base + 1 < NNODES) excl[base + 1] = e1;
            if (base + 2 < NNODES) excl[base + 2] = e2;
            if (base + 3 < NNODES) excl[base + 3] = e3;
        }
        if (tid == 0) bsum[b] = wsum[0] + wsum[1] + wsum[2] + wsum[3];
    }

    // ---- streaming side-work: zero agg + compute fp8 th table ----
    const int gid = blockIdx.x * 256 + tid;
    const uint4 z = make_uint4(0u, 0u, 0u, 0u);
    for (size_t i = gid; i < (size_t)NNODES * 16; i += (size_t)gridDim.x * 256)
        agg4[i] = z;

    const int lane = tid & 63;
    const int wv   = tid >> 6;
    const int c0 = lane * 2, c1 = c0 + 1;
    float wxa[DXI], wxb_[DXI];
#pragma unroll
    for (int k = 0; k < DXI; ++k) { wxa[k] = Wx[k * H + c0]; wxb_[k] = Wx[k * H + c1]; }
    const float wp00 = Wp[c0], wp01 = Wp[H + c0];
    const float wp10 = Wp[c1], wp11 = Wp[H + c1];

    for (int n = blockIdx.x * 4 + wv; n < NNODES; n += gridDim.x * 4) {
        const float* xr = x + (size_t)n * DXI;
        const float px = pos[(size_t)n * 3], py = pos[(size_t)n * 3 + 1];
        float a0 = fmaf(wp00, px, wp01 * py);
        float a1 = fmaf(wp10, px, wp11 * py);
#pragma unroll
        for (int k = 0; k < DXI; ++k) {
            const float xv = xr[k];
            a0 = fmaf(xv, wxa[k], a0);
            a1 = fmaf(xv, wxb_[k], a1);
        }
        const __hip_fp8_e4m3 q0(fast_tanh(a0));
        const __hip_fp8_e4m3 q1(fast_tanh(a1));
        th[(size_t)n * 64 + lane] =
            (unsigned short)((unsigned)q0.__x | ((unsigned)q1.__x << 8));
    }
}

// ---------------------------------------------------------------------------
// CSR build pass 2b: exclusive scan of block totals (1 block).
// ---------------------------------------------------------------------------
__global__ __launch_bounds__(128) void scan2_kernel(int* __restrict__ bsum)
{
    const int tid = threadIdx.x;
    int v = (tid < NSB) ? bsum[tid] : 0;
    const int own = v;
    const int lane = tid & 63, wv = tid >> 6;
#pragma unroll
    for (int d = 1; d < 64; d <<= 1) {
        const int t = __shfl_up(v, d);
        if (lane >= d) v += t;
    }
    __shared__ int ws2[2];
    if (lane == 63) ws2[wv] = v;
    __syncthreads();
    if (wv == 1) v += ws2[0];
    if (tid < NSB) bsum[tid] = v - own;
}

// ---------------------------------------------------------------------------
// CSR build pass 2c: add block offsets; produce cursor[].
// ---------------------------------------------------------------------------
__global__ __launch_bounds__(256) void scan3_kernel(
    int* __restrict__ offsets, int* __restrict__ cursor, const int* __restrict__ bsum)
{
    const int tid = threadIdx.x, b = blockIdx.x;
    const int base = b * 1024 + tid * 4;
    const int add = bsum[b];
    if (base + 3 < NNODES) {
        int4 t = *(const int4*)(offsets + base);
        t.x += add; t.y += add; t.z += add; t.w += add;
        *(int4*)(offsets + base) = t;
        *(int4*)(cursor + base) = t;
    } else {
        for (int i = 0; i < 4; ++i)
            if (base + i < NNODES) {
                const int t = offsets[base + i] + add;
                offsets[base + i] = t;
                cursor[base + i] = t;
            }
    }
}

// ---------------------------------------------------------------------------
// Pass 2 scatter: range r's records are contiguous in epack; blocks with
// bid%8 == r (one XCD under round-robin) read sequentially and scatter into
// csrE's 1MB range region — cursor atomics and destination lines stay
// XCD-L2-local, lines accumulate fully before write-back.
// ---------------------------------------------------------------------------
__global__ __launch_bounds__(256) void scatter2_kernel(
    const uint2* __restrict__ epack, const int* __restrict__ gcur,
    int* __restrict__ cursor, uint2* __restrict__ csrE)
{
    const int r = blockIdx.x & 7;
    const int g = blockIdx.x >> 3;
    const int G = gridDim.x >> 3;
    const int rcnt = gcur[r];
    for (int i = g * 256 + threadIdx.x; i < rcnt; i += G * 256) {
        const uint2 v = epack[(size_t)r * RCAP + i];
        const int d = (int)((v.x >> 17) | ((v.y & 3u) << 15));
        const int slot = atomicAdd(&cursor[d], 1);
        csrE[slot] = v;
    }
}

// ---------------------------------------------------------------------------
// Segmented edge kernel: one WAVE per 64-edge dst-sorted run. 8B records;
// coalesced fp8 th-row reads (16-deep batches), readlane broadcast,
// segmented flush to agg[dst] (bf16x2).
// ---------------------------------------------------------------------------
__global__ __launch_bounds__(256) void seg_edge_kernel(
    const uint2* __restrict__ csrE, const unsigned short* __restrict__ th,
    const float* __restrict__ We, unsigned* __restrict__ agg)
{
    const int run = blockIdx.x * 4 + (threadIdx.x >> 6);
    if (run >= NRUNS) return;
    const int lane = threadIdx.x & 63;
    const int c0 = lane * 2, c1 = c0 + 1;

    const float wea0 = We[c0], wea1 = We[H + c0], wea2 = We[2 * H + c0];
    const float web0 = We[c1], web1 = We[H + c1], web2 = We[2 * H + c1];

    const uint2 rec = csrE[(size_t)run * 64 + lane];
    const int mysrc = (int)(rec.x & 0x1FFFFu);
    const int mydst = (int)((rec.x >> 17) | ((rec.y & 3u) << 15));

    float acc0 = 0.f, acc1 = 0.f;
    bool first = true;
    int cur = __builtin_amdgcn_readlane(mydst, 0);

#pragma unroll
    for (int sub = 0; sub < 4; ++sub) {
        unsigned short rowv[16];
#pragma unroll
        for (int t = 0; t < 16; ++t) {
            const int s = __builtin_amdgcn_readlane(mysrc, sub * 16 + t);
            rowv[t] = th[(size_t)s * 64 + lane];
        }
#pragma unroll
        for (int t = 0; t < 16; ++t) {
            const int e = sub * 16 + t;
            const unsigned hi = (unsigned)__builtin_amdgcn_readlane((int)rec.y, e);
            const float e0f = fp8_dec((hi >> 2) & 0xffu);
            const float e1f = fp8_dec((hi >> 10) & 0xffu);
            const float e3f = fp8_dec((hi >> 18) & 0xffu);
            const float th0 = fp8_dec(rowv[t] & 0xffu);
            const float th1 = fp8_dec((unsigned)rowv[t] >> 8);
            const float w0 = fmaf(e0f, wea0, fmaf(e1f, wea1, e3f * wea2));
            const float w1 = fmaf(e0f, web0, fmaf(e1f, web1, e3f * web2));
            acc0 = fmaf(th0, w0, acc0);
            acc1 = fmaf(th1, w1, acc1);

            const int nxt = (e < 63) ? __builtin_amdgcn_readlane(mydst, e + 1) : -1;
            if (nxt != cur) {
                unsigned* p = agg + (size_t)cur * 64 + lane;
                if (first || e == 63) {
                    unsigned old = *p;
                    while (true) {
                        const float g0 = __uint_as_float(old << 16) + acc0;
                        const float g1 = __uint_as_float(old & 0xffff0000u) + acc1;
                        const unsigned nw = pack_bf16(g0, g1);
                        const unsigned prev = atomicCAS(p, old, nw);
                        if (prev == old) break;
                        old = prev;
                    }
                } else {
                    *p = pack_bf16(acc0, acc1);
                }
                acc0 = 0.f; acc1 = 0.f;
                first = false;
                cur = nxt;
            }
        }
    }
}

// ---------------------------------------------------------------------------
// Node kernel: wave per node, 2ch/lane. ctx via LDS reduce + per-block row.
// ---------------------------------------------------------------------------
__global__ __launch_bounds__(256) void node_kernel(
    const float* __restrict__ x, const float* __restrict__ pos,
    const unsigned* __restrict__ agg,
    const float* __restrict__ Wx, const float* __restrict__ Wp,
    const float* __restrict__ Wout,
    float* __restrict__ out_sup, float* __restrict__ ctx_part)
{
    const int lane = threadIdx.x & 63;
    const int wv   = threadIdx.x >> 6;
    const int c0 = lane * 2, c1 = c0 + 1;

    float wxa[DXI], wxb_[DXI];
#pragma unroll
    for (int k = 0; k < DXI; ++k) { wxa[k] = Wx[k * H + c0]; wxb_[k] = Wx[k * H + c1]; }
    const float wp00 = Wp[c0], wp01 = Wp[H + c0];
    const float wp10 = Wp[c1], wp11 = Wp[H + c1];
    const float woa0 = Wout[c0 * 3], woa1 = Wout[c0 * 3 + 1], woa2 = Wout[c0 * 3 + 2];
    const float wob0 = Wout[c1 * 3], wob1 = Wout[c1 * 3 + 1], wob2 = Wout[c1 * 3 + 2];

    float ctx0 = 0.f, ctx1 = 0.f;

    for (int n = blockIdx.x * 4 + wv; n < NNODES; n += gridDim.x * 4) {
        const unsigned ag = agg[(size_t)n * 64 + lane];
        const float* xr = x + (size_t)n * DXI;
        const float px = pos[(size_t)n * 3], py = pos[(size_t)n * 3 + 1];
        float a0 = fmaf(wp00, px, wp01 * py);
        float a1 = fmaf(wp10, px, wp11 * py);
#pragma unroll
        for (int k = 0; k < DXI; ++k) {
            const float xv = xr[k];
            a0 = fmaf(xv, wxa[k], a0);
            a1 = fmaf(xv, wxb_[k], a1);
        }
        const float h0 = fast_tanh(fast_tanh(a0) + __uint_as_float(ag << 16));
        const float h1 = fast_tanh(fast_tanh(a1) + __uint_as_float(ag & 0xffff0000u));
        ctx0 += h0; ctx1 += h1;

        float p0 = fmaf(h0, woa0, h1 * wob0);
        float p1 = fmaf(h0, woa1, h1 * wob1);
        float p2 = fmaf(h0, woa2, h1 * wob2);
#pragma unroll
        for (int m = 32; m; m >>= 1) {
            p0 += __shfl_xor(p0, m);
            p1 += __shfl_xor(p1, m);
            p2 += __shfl_xor(p2, m);
        }
        if (lane == 0) {
            out_sup[(size_t)n * 3 + 0] = p0;
            out_sup[(size_t)n * 3 + 1] = p1;
            out_sup[(size_t)n * 3 + 2] = p2;
        }
    }

    __shared__ float part[4][H];
    part[wv][c0] = ctx0;
    part[wv][c1] = ctx1;
    __syncthreads();
    if (threadIdx.x < H) {
        const int ch = threadIdx.x;
        ctx_part[(size_t)blockIdx.x * H + ch] =
            part[0][ch] + part[1][ch] + part[2][ch] + part[3][ch];
    }
}

// ---------------------------------------------------------------------------
// ctx finalize: sum per-block partial rows, then tab rows.
// ---------------------------------------------------------------------------
__global__ __launch_bounds__(128) void ctx_kernel(
    const float* __restrict__ ctx_part, const float* __restrict__ W1,
    const float* __restrict__ b1, float* __restrict__ tab)
{
    __shared__ float ctx[H];
    const int ch = threadIdx.x;
    float s0 = 0.f, s1 = 0.f, s2 = 0.f, s3 = 0.f;
#pragma unroll 4
    for (int b = 0; b < NODE_BLOCKS; b += 4) {
        s0 += ctx_part[(size_t)(b + 0) * H + ch];
        s1 += ctx_part[(size_t)(b + 1) * H + ch];
        s2 += ctx_part[(size_t)(b + 2) * H + ch];
        s3 += ctx_part[(size_t)(b + 3) * H + ch];
    }
    ctx[ch] = (s0 + s1 + s2 + s3) * (1.0f / (float)NNODES);
    __syncthreads();
    float acc = b1[ch];
    for (int k = 0; k < H; ++k) acc = fmaf(ctx[k], W1[(size_t)(2 + k) * H + ch], acc);
    const float A0 = W1[ch], A1 = W1[H + ch];
    tab[ch * 8 + 0] = A0;
    tab[ch * 8 + 1] = A1;
    tab[ch * 8 + 2] = acc;
    tab[ch * 8 + 3] = A0 * A0;
    tab[ch * 8 + 4] = A1 * A1;
    tab[ch * 8 + 5] = 0.f;
    tab[ch * 8 + 6] = 0.f;
    tab[ch * 8 + 7] = 0.f;
}

// ---------------------------------------------------------------------------
// Sampling kernel (MFMA): block = 32 points, 256 thr = 4 waves.
// 5 GEMMs C_q = A_q x W2 share one B (bf16 W2^T in LDS). Epilogue:
// tanh/physics in-register, shfl j-reduce, LDS cross-wave combine, direct
// out writes (incl. boundary residuals).
// ---------------------------------------------------------------------------
__global__ __launch_bounds__(256, 2) void samp_mfma_kernel(
    const float* __restrict__ dom, const float* __restrict__ bnd,
    const int* __restrict__ bidx,
    const float* __restrict__ x, const float* __restrict__ xmask,
    const float* __restrict__ tab,
    const float* __restrict__ W2, const float* __restrict__ b2,
    const float* __restrict__ W3, float* __restrict__ out)
{
    __shared__ __attribute__((aligned(16))) short Bt[128 * KPAD];     // 34816 B
    __shared__ __attribute__((aligned(16))) short Alds[5 * A_STRIDE]; // 43520 B
    __shared__ __attribute__((aligned(16))) float red[32][13];        // 1664 B

    const int tid = threadIdx.x;
    const int blk = blockIdx.x;

    // phase 0a: W2 -> Bt (transposed, bf16)
    for (int i = tid; i < H * H; i += 256) {
        const int k = i >> 7, n = i & 127;
        Bt[n * KPAD + k] = to_bf16(W2[i]);
    }

    // phase 0b: generate 5 A matrices for this block's 32 points
    for (int idx = tid; idx < 32 * 64; idx += 256) {
        const int pl = idx >> 6;
        const int k0 = (idx & 63) * 2;
        const int p  = blk * 32 + pl;
        float spx, spy;
        if (p < NDOM) { spx = dom[(size_t)p * 2];          spy = dom[(size_t)p * 2 + 1]; }
        else          { spx = bnd[(size_t)(p - NDOM) * 2]; spy = bnd[(size_t)(p - NDOM) * 2 + 1]; }
        float v[2][5];
#pragma unroll
        for (int kk = 0; kk < 2; ++kk) {
            const int k = k0 + kk;
            const float4 t4 = *(const float4*)(tab + (size_t)k * 8);
            const float A1s = tab[(size_t)k * 8 + 4];
            const float A0 = t4.x, A1 = t4.y, cc = t4.z, A0s = t4.w;
            const float a1 = fmaf(spx, A0, fmaf(spy, A1, cc));
            const float e  = __builtin_amdgcn_exp2f(a1 * 2.88539008f);
            const float h1 = fmaf(-2.f, __builtin_amdgcn_rcpf(e + 1.f), 1.f);
            const float t1 = fmaf(-h1, h1, 1.f);
            const float m2 = -2.f * h1 * t1;
            v[kk][0] = h1;
            v[kk][1] = t1 * A0;
            v[kk][2] = t1 * A1;
            v[kk][3] = m2 * A0s;
            v[kk][4] = m2 * A1s;
        }
        const int base = pl * KPAD + k0;
#pragma unroll
        for (int q = 0; q < 5; ++q)
            *(unsigned*)&Alds[q * A_STRIDE + base] = pack_bf16(v[0][q], v[1][q]);
    }
    __syncthreads();

    // phase 1: MFMA. wave = (pt, jh): 16 points x 64 j.
    const int lane = tid & 63;
    const int wv = tid >> 6;
    const int pt = wv >> 1;
    const int jh = wv & 1;
    const int ln = lane & 15;
    const int hi = lane >> 4;

    f32x4 acc[4][5];
#pragma unroll
    for (int nt = 0; nt < 4; ++nt)
#pragma unroll
        for (int q = 0; q < 5; ++q)
            acc[nt][q] = (f32x4){0.f, 0.f, 0.f, 0.f};

#pragma unroll
    for (int kc = 0; kc < 4; ++kc) {
        short8 af[5];
#pragma unroll
        for (int q = 0; q < 5; ++q)
            af[q] = *(const short8*)&Alds[q * A_STRIDE + (pt * 16 + ln) * KPAD + kc * 32 + hi * 8];
        short8 bfr[4];
#pragma unroll
        for (int nt = 0; nt < 4; ++nt)
            bfr[nt] = *(const short8*)&Bt[(jh * 64 + nt * 16 + ln) * KPAD + kc * 32 + hi * 8];
#pragma unroll
        for (int nt = 0; nt < 4; ++nt)
#pragma unroll
            for (int q = 0; q < 5; ++q)
                acc[nt][q] = __builtin_amdgcn_mfma_f32_16x16x32_bf16(af[q], bfr[nt], acc[nt][q], 0, 0, 0);
    }

    // phase 2: epilogue. lane holds (j = jh*64+nt*16+ln, 4 points via regs).
    float w30[4], w31[4], w32[4], b2j[4];
#pragma unroll
    for (int nt = 0; nt < 4; ++nt) {
        const int j = jh * 64 + nt * 16 + ln;
        w30[nt] = W3[j * 3];
        w31[nt] = W3[j * 3 + 1];
        w32[nt] = W3[j * 3 + 2];
        b2j[nt] = b2[j];
    }

    float rr[4][13];
#pragma unroll
    for (int i = 0; i < 4; ++i)
#pragma unroll
        for (int c = 0; c < 13; ++c) rr[i][c] = 0.f;

#pragma unroll
    for (int i = 0; i < 4; ++i) {
#pragma unroll
        for (int nt = 0; nt < 4; ++nt) {
            const float a2v  = acc[nt][0][i] + b2j[nt];
            const float d2xv = acc[nt][1][i];
            const float d2yv = acc[nt][2][i];
            const float exxv = acc[nt][3][i];
            const float eyyv = acc[nt][4][i];
            const float h2 = fast_tanh(a2v);
            const float t2 = fmaf(-h2, h2, 1.f);
            const float gx = t2 * d2xv;
            const float gy = t2 * d2yv;
            const float hxx = fmaf(-2.f * h2 * gx, d2xv, t2 * exxv);
            const float hyy = fmaf(-2.f * h2 * gy, d2yv, t2 * eyyv);
            rr[i][0]  = fmaf(h2, w30[nt], rr[i][0]);
            rr[i][1]  = fmaf(h2, w31[nt], rr[i][1]);
            rr[i][2]  = fmaf(h2, w32[nt], rr[i][2]);
            rr[i][3]  = fmaf(gx, w30[nt], rr[i][3]);
            rr[i][4]  = fmaf(gx, w31[nt], rr[i][4]);
            rr[i][5]  = fmaf(gx, w32[nt], rr[i][5]);
            rr[i][6]  = fmaf(gy, w30[nt], rr[i][6]);
            rr[i][7]  = fmaf(gy, w31[nt], rr[i][7]);
            rr[i][8]  = fmaf(gy, w32[nt], rr[i][8]);
            rr[i][9]  = fmaf(hxx, w30[nt], rr[i][9]);
            rr[i][10] = fmaf(hxx, w31[nt], rr[i][10]);
            rr[i][11] = fmaf(hyy, w30[nt], rr[i][11]);
            rr[i][12] = fmaf(hyy, w31[nt], rr[i][12]);
        }
    }

    // reduce over the 16 j-lanes
#pragma unroll
    for (int m = 1; m < 16; m <<= 1)
#pragma unroll
        for (int i = 0; i < 4; ++i)
#pragma unroll
            for (int c = 0; c < 13; ++c)
                rr[i][c] += __shfl_xor(rr[i][c], m);

    if (ln == 0 && jh == 0) {
#pragma unroll
        for (int i = 0; i < 4; ++i) {
            const int pl = pt * 16 + hi * 4 + i;
#pragma unroll
            for (int c = 0; c < 13; ++c) red[pl][c] = rr[i][c];
        }
    }
    __syncthreads();
    if (ln == 0 && jh == 1) {
#pragma unroll
        for (int i = 0; i < 4; ++i) {
            const int pl = pt * 16 + hi * 4 + i;
#pragma unroll
            for (int c = 0; c < 13; ++c) red[pl][c] += rr[i][c];
        }
    }
    __syncthreads();

    // phase 3: physics + writes, one thread per point
    if (tid < 32) {
        const int p = blk * 32 + tid;
        float s[13];
#pragma unroll
        for (int c = 0; c < 13; ++c) s[c] = red[tid][c];
        const float u = s[0], v = s[1], pp = s[2];
        const float ux = s[3], vx = s[4], px = s[5];
        const float uy = s[6], vy = s[7], py = s[8];
        const float uxx = s[9], vxx = s[10], uyy = s[11], vyy = s[12];
        if (p < NDOM) {
            out[CONT_OFF + p] = ux + vy;
            out[MOMX_OFF + p] = fmaf(u, ux, fmaf(v, uy, px)) - (uxx + uyy) * INV_RE;
            out[MOMY_OFF + p] = fmaf(u, vx, fmaf(v, vy, py)) - (vxx + vyy) * INV_RE;
        } else {
            const int i = p - NDOM;
            const int idx = bidx[i];
            const float* xbp = x + (size_t)idx * DXI;
            const float* mm = xmask + (size_t)idx * 6;
            const float tx = xbp[0], ty = xbp[1];
            const float nx = -ty, ny = tx;
            const float r_vt = fabsf(tx * u + ty * v - xbp[2]) * mm[1];
            const float r_vn = fabsf(nx * u + ny * v - xbp[3]) * mm[2];
            const float r_p  = fabsf(pp - xbp[4]) * mm[3];
            const float r_dv = fabsf(nx * ux + ny * vy - xbp[5]) * mm[4];
            const float r_dp = fabsf(nx * px + ny * py - xbp[6]) * mm[5];
            const float c = mm[1] + mm[2] + mm[3] + mm[4] + mm[5];
            out[BND_OFF + i] = (r_vt + r_vn + r_p + r_dv + r_dp) / c;
        }
    }
}

extern "C" void kernel_launch(void* const* d_in, const int* in_sizes, int n_in,
                              void* d_out, int out_size, void* d_ws, size_t ws_size,
                              hipStream_t stream) {
    const float* x     = (const float*)d_in[0];
    const float* xmask = (const float*)d_in[1];
    const int*   eidx  = (const int*)d_in[2];
    const float* eattr = (const float*)d_in[3];
    const float* pos   = (const float*)d_in[4];
    const float* dom   = (const float*)d_in[6];
    const float* bnd   = (const float*)d_in[7];
    const int*   bidx  = (const int*)d_in[8];
    const float* Wx    = (const float*)d_in[9];
    const float* Wp    = (const float*)d_in[10];
    const float* We    = (const float*)d_in[11];
    const float* Wout  = (const float*)d_in[12];
    const float* W1    = (const float*)d_in[13];
    const float* b1    = (const float*)d_in[14];
    const float* W2    = (const float*)d_in[15];
    const float* b2    = (const float*)d_in[16];
    const float* W3    = (const float*)d_in[17];

    float* out = (float*)d_out;

    // workspace layout (16B-aligned sections): total ~57 MB
    int*            counts   = (int*)d_ws;                    // NNODES
    int*            gcur     = counts + NNODES;               // 8
    int*            offsets  = gcur + 8;                      // NNODES + 8
    int*            cursor   = offsets + NNODES + 8;          // NNODES
    int*            bsum     = cursor + NNODES;               // 128
    uint2*          csrE     = (uint2*)(bsum + 128);          // NEDGES uint2 (8 MB)
    uint2*          epack    = csrE + NEDGES;                 // 8*RCAP uint2 (8.4 MB)
    unsigned short* th       = (unsigned short*)(epack + 8 * RCAP); // NNODES*64 ushort (12.8 MB)
    unsigned*       agg      = (unsigned*)(th + (size_t)NNODES * 64); // NNODES*64 (25.6 MB)
    float*          ctx_part = (float*)(agg + (size_t)NNODES * 64);   // NODE_BLOCKS*H (512 KB)
    float*          tab      = ctx_part + (size_t)NODE_BLOCKS * H;    // H*8

    (void)hipMemsetAsync(counts, 0, (size_t)(NNODES + 8) * sizeof(int), stream);

    bucket_hist_kernel<<<(NEDGES + 1023) / 1024, 256, 0, stream>>>(eidx, eattr, counts, gcur, epack);
    scan1_kernel<<<2048, 256, 0, stream>>>(counts, offsets, bsum, x, pos, Wx, Wp, th, (uint4*)agg);
    scan2_kernel<<<1, 128, 0, stream>>>(bsum);
    scan3_kernel<<<NSB, 256, 0, stream>>>(offsets, cursor, bsum);
    scatter2_kernel<<<4096, 256, 0, stream>>>(epack, gcur, cursor, csrE);
    seg_edge_kernel<<<(NRUNS + 3) / 4, 256, 0, stream>>>(csrE, th, We, agg);
    node_kernel<<<NODE_BLOCKS, 256, 0, stream>>>(x, pos, agg, Wx, Wp, Wout, out, ctx_part);
    ctx_kernel<<<1, H, 0, stream>>>(ctx_part, W1, b1, tab);
    samp_mfma_kernel<<<NPTS / 32, 256, 0, stream>>>(dom, bnd, bidx, x, xmask, tab, W2, b2, W3, out);
}

// Round 24
// 248.208 us; speedup vs baseline: 1.1016x; 1.1016x over previous
//
#include <hip/hip_runtime.h>
#include <hip/hip_fp8.h>
#include <math.h>

#define H 128
#define DXI 8
#define NNODES 100000
#define NEDGES 1000000
#define NRUNS (NEDGES / 64)
#define NDOM 32768
#define NBND 8192
#define NPTS (NDOM + NBND)
#define INV_RE 1.45e-05f
#define NODE_BLOCKS 1024
#define NPR (NNODES / 8)        // dst range size per partition = 12500

#define NSB ((NNODES + 1023) / 1024)   // scan blocks (1024 elems each) = 98

// d_out layout (floats): out_sup[300000] | continuity[32768] | momx[32768] | momy[32768] | boundary[8192]
#define CONT_OFF (NNODES * 3)
#define MOMX_OFF (CONT_OFF + NDOM)
#define MOMY_OFF (MOMX_OFF + NDOM)
#define BND_OFF  (MOMY_OFF + NDOM)

#define KPAD 136                 // halves per LDS row (128 + 8 pad -> 272B, 16B mult)
#define A_STRIDE (32 * KPAD)     // halves per A matrix

typedef __attribute__((ext_vector_type(8))) short short8;
typedef __attribute__((ext_vector_type(4))) float f32x4;

// fast tanh: 1 - 2/(exp2(2x*log2e)+1). Saturates correctly at +/-inf.
__device__ __forceinline__ float fast_tanh(float x) {
    const float e = __builtin_amdgcn_exp2f(x * 2.88539008f);
    return fmaf(-2.f, __builtin_amdgcn_rcpf(e + 1.f), 1.f);
}

// pack two floats to bf16 pair (RNE), low word = a, high word = b
__device__ __forceinline__ unsigned pack_bf16(float a, float b) {
    unsigned ua = __float_as_uint(a), ub = __float_as_uint(b);
    ua += 0x7fffu + ((ua >> 16) & 1u);
    ub += 0x7fffu + ((ub >> 16) & 1u);
    return (ua >> 16) | (ub & 0xffff0000u);
}

__device__ __forceinline__ short to_bf16(float f) {
    unsigned u = __float_as_uint(f);
    u += 0x7fffu + ((u >> 16) & 1u);
    return (short)(u >> 16);
}

__device__ __forceinline__ float fp8_dec(unsigned b) {
    __hip_fp8_e4m3 d;
    d.__x = (__hip_fp8_storage_t)b;
    return (float)d;
}

// ---------------------------------------------------------------------------
// th table (fp8, 2ch/lane in ushort) + UNpartitioned dst histogram +
// agg zero-init (fused). Grid 2048 for occupancy. Histogram reads dst once
// (4 MB) and issues 1M int atomics on the 400 KB counts region.
// ---------------------------------------------------------------------------
__global__ __launch_bounds__(256) void hist_th_kernel(
    const int* __restrict__ eidx, const float* __restrict__ x,
    const float* __restrict__ pos,
    const float* __restrict__ Wx, const float* __restrict__ Wp,
    int* __restrict__ counts, unsigned short* __restrict__ th,
    uint4* __restrict__ agg4)
{
    const int lane = threadIdx.x & 63;
    const int wv   = threadIdx.x >> 6;
    const int c0 = lane * 2, c1 = c0 + 1;

    // zero agg (overlapped with compute below)
    const int gid = blockIdx.x * 256 + threadIdx.x;
    const uint4 z = make_uint4(0u, 0u, 0u, 0u);
    for (size_t i = gid; i < (size_t)NNODES * 16; i += (size_t)gridDim.x * 256)
        agg4[i] = z;

    float wxa[DXI], wxb_[DXI];
#pragma unroll
    for (int k = 0; k < DXI; ++k) { wxa[k] = Wx[k * H + c0]; wxb_[k] = Wx[k * H + c1]; }
    const float wp00 = Wp[c0], wp01 = Wp[H + c0];
    const float wp10 = Wp[c1], wp11 = Wp[H + c1];

    for (int n = blockIdx.x * 4 + wv; n < NNODES; n += gridDim.x * 4) {
        const float* xr = x + (size_t)n * DXI;
        const float px = pos[(size_t)n * 3], py = pos[(size_t)n * 3 + 1];
        float a0 = fmaf(wp00, px, wp01 * py);
        float a1 = fmaf(wp10, px, wp11 * py);
#pragma unroll
        for (int k = 0; k < DXI; ++k) {
            const float xv = xr[k];
            a0 = fmaf(xv, wxa[k], a0);
            a1 = fmaf(xv, wxb_[k], a1);
        }
        const __hip_fp8_e4m3 q0(fast_tanh(a0));
        const __hip_fp8_e4m3 q1(fast_tanh(a1));
        th[(size_t)n * 64 + lane] =
            (unsigned short)((unsigned)q0.__x | ((unsigned)q1.__x << 8));
    }

    // unpartitioned histogram: read dst once, 1M atomics on 400 KB target
    const int* dst = eidx + NEDGES;
    for (int e = gid; e < NEDGES; e += gridDim.x * 256)
        atomicAdd(&counts[dst[e]], 1);
}

// ---------------------------------------------------------------------------
// CSR build pass 2a: per-block exclusive scan (1024 elems/block).
// ---------------------------------------------------------------------------
__global__ __launch_bounds__(256) void scan1_kernel(
    const int* __restrict__ counts, int* __restrict__ excl, int* __restrict__ bsum)
{
    const int tid = threadIdx.x, b = blockIdx.x;
    const int base = b * 1024 + tid * 4;
    int v0 = 0, v1 = 0, v2 = 0, v3 = 0;
    if (base + 3 < NNODES) {
        const int4 t = *(const int4*)(counts + base);
        v0 = t.x; v1 = t.y; v2 = t.z; v3 = t.w;
    } else {
        if (base     < NNODES) v0 = counts[base];
        if (base + 1 < NNODES) v1 = counts[base + 1];
        if (base + 2 < NNODES) v2 = counts[base + 2];
        if (base + 3 < NNODES) v3 = counts[base + 3];
    }
    const int own = v0 + v1 + v2 + v3;
    int s = own;
    const int lane = tid & 63, wv = tid >> 6;
#pragma unroll
    for (int d = 1; d < 64; d <<= 1) {
        const int t = __shfl_up(s, d);
        if (lane >= d) s += t;
    }
    __shared__ int wsum[4];
    if (lane == 63) wsum[wv] = s;
    __syncthreads();
    int woff = 0;
    for (int w = 0; w < wv; ++w) woff += wsum[w];
    const int e0 = s - own + woff;
    const int e1 = e0 + v0, e2 = e1 + v1, e3 = e2 + v2;
    if (base + 3 < NNODES) {
        *(int4*)(excl + base) = make_int4(e0, e1, e2, e3);
    } else {
        if (base     < NNODES) excl[base]     = e0;
        if (base + 1 < NNODES) excl[base + 1] = e1;
        if (base + 2 < NNODES) excl[base + 2] = e2;
        if (base + 3 < NNODES) excl[base + 3] = e3;
    }
    if (tid == 0) bsum[b] = wsum[0] + wsum[1] + wsum[2] + wsum[3];
}

// ---------------------------------------------------------------------------
// CSR build pass 2b: exclusive scan of block totals (1 block).
// ---------------------------------------------------------------------------
__global__ __launch_bounds__(128) void scan2_kernel(int* __restrict__ bsum)
{
    const int tid = threadIdx.x;
    int v = (tid < NSB) ? bsum[tid] : 0;
    const int own = v;
    const int lane = tid & 63, wv = tid >> 6;
#pragma unroll
    for (int d = 1; d < 64; d <<= 1) {
        const int t = __shfl_up(v, d);
        if (lane >= d) v += t;
    }
    __shared__ int ws2[2];
    if (lane == 63) ws2[wv] = v;
    __syncthreads();
    if (wv == 1) v += ws2[0];
    if (tid < NSB) bsum[tid] = v - own;
}

// ---------------------------------------------------------------------------
// CSR build pass 2c: add block offsets; produce cursor[].
// ---------------------------------------------------------------------------
__global__ __launch_bounds__(256) void scan3_kernel(
    int* __restrict__ offsets, int* __restrict__ cursor, const int* __restrict__ bsum)
{
    const int tid = threadIdx.x, b = blockIdx.x;
    const int base = b * 1024 + tid * 4;
    const int add = bsum[b];
    if (base + 3 < NNODES) {
        int4 t = *(const int4*)(offsets + base);
        t.x += add; t.y += add; t.z += add; t.w += add;
        *(int4*)(offsets + base) = t;
        *(int4*)(cursor + base) = t;
    } else {
        for (int i = 0; i < 4; ++i)
            if (base + i < NNODES) {
                const int t = offsets[base + i] + add;
                offsets[base + i] = t;
                cursor[base + i] = t;
            }
    }
}

// ---------------------------------------------------------------------------
// CSR build pass 3 (range-partitioned strided scatter, 8B packed records):
// block (g = blockIdx>>3, r = blockIdx&7) sweeps the edge stride-set,
// scattering only dsts in range r. Record: 58-bit pack
// {src:17 | dst:17 | fp8 e0,e1,e3} in uint2. Grid 8192 for latency hiding.
// ---------------------------------------------------------------------------
__global__ __launch_bounds__(256) void scatter_kernel(
    const int* __restrict__ eidx, const float* __restrict__ eattr,
    int* __restrict__ cursor, uint2* __restrict__ csrE)
{
    const int* dst = eidx + NEDGES;
    const int G   = gridDim.x >> 3;
    const int g   = blockIdx.x >> 3;
    const int r   = blockIdx.x & 7;
    const int dlo = r * NPR, dhi = dlo + NPR;
    for (int e = g * 256 + threadIdx.x; e < NEDGES; e += G * 256) {
        const int d = dst[e];
        if (d >= dlo && d < dhi) {
            const float4 ea = ((const float4*)eattr)[e];
            const int slot = atomicAdd(&cursor[d], 1);
            const __hip_fp8_e4m3 f0(ea.x), f1(ea.y), f3(ea.w);
            const unsigned long long v =
                (unsigned long long)(unsigned)eidx[e]
              | ((unsigned long long)(unsigned)d << 17)
              | ((unsigned long long)f0.__x << 34)
              | ((unsigned long long)f1.__x << 42)
              | ((unsigned long long)f3.__x << 50);
            csrE[slot] = make_uint2((unsigned)v, (unsigned)(v >> 32));
        }
    }
}

// ---------------------------------------------------------------------------
// Segmented edge kernel: one WAVE per 64-edge dst-sorted run. 8B records;
// coalesced fp8 th-row reads (16-deep batches), readlane broadcast,
// segmented flush to agg[dst] (bf16x2).
// ---------------------------------------------------------------------------
__global__ __launch_bounds__(256) void seg_edge_kernel(
    const uint2* __restrict__ csrE, const unsigned short* __restrict__ th,
    const float* __restrict__ We, unsigned* __restrict__ agg)
{
    const int run = blockIdx.x * 4 + (threadIdx.x >> 6);
    if (run >= NRUNS) return;
    const int lane = threadIdx.x & 63;
    const int c0 = lane * 2, c1 = c0 + 1;

    const float wea0 = We[c0], wea1 = We[H + c0], wea2 = We[2 * H + c0];
    const float web0 = We[c1], web1 = We[H + c1], web2 = We[2 * H + c1];

    const uint2 rec = csrE[(size_t)run * 64 + lane];
    const int mysrc = (int)(rec.x & 0x1FFFFu);
    const int mydst = (int)((rec.x >> 17) | ((rec.y & 3u) << 15));

    float acc0 = 0.f, acc1 = 0.f;
    bool first = true;
    int cur = __builtin_amdgcn_readlane(mydst, 0);

#pragma unroll
    for (int sub = 0; sub < 4; ++sub) {
        unsigned short rowv[16];
#pragma unroll
        for (int t = 0; t < 16; ++t) {
            const int s = __builtin_amdgcn_readlane(mysrc, sub * 16 + t);
            rowv[t] = th[(size_t)s * 64 + lane];
        }
#pragma unroll
        for (int t = 0; t < 16; ++t) {
            const int e = sub * 16 + t;
            const unsigned hi = (unsigned)__builtin_amdgcn_readlane((int)rec.y, e);
            const float e0f = fp8_dec((hi >> 2) & 0xffu);
            const float e1f = fp8_dec((hi >> 10) & 0xffu);
            const float e3f = fp8_dec((hi >> 18) & 0xffu);
            const float th0 = fp8_dec(rowv[t] & 0xffu);
            const float th1 = fp8_dec((unsigned)rowv[t] >> 8);
            const float w0 = fmaf(e0f, wea0, fmaf(e1f, wea1, e3f * wea2));
            const float w1 = fmaf(e0f, web0, fmaf(e1f, web1, e3f * web2));
            acc0 = fmaf(th0, w0, acc0);
            acc1 = fmaf(th1, w1, acc1);

            const int nxt = (e < 63) ? __builtin_amdgcn_readlane(mydst, e + 1) : -1;
            if (nxt != cur) {
                unsigned* p = agg + (size_t)cur * 64 + lane;
                if (first || e == 63) {
                    unsigned old = *p;
                    while (true) {
                        const float g0 = __uint_as_float(old << 16) + acc0;
                        const float g1 = __uint_as_float(old & 0xffff0000u) + acc1;
                        const unsigned nw = pack_bf16(g0, g1);
                        const unsigned prev = atomicCAS(p, old, nw);
                        if (prev == old) break;
                        old = prev;
                    }
                } else {
                    *p = pack_bf16(acc0, acc1);
                }
                acc0 = 0.f; acc1 = 0.f;
                first = false;
                cur = nxt;
            }
        }
    }
}

// ---------------------------------------------------------------------------
// Node kernel: wave per node, 2ch/lane. ctx via LDS reduce + per-block row.
// ---------------------------------------------------------------------------
__global__ __launch_bounds__(256) void node_kernel(
    const float* __restrict__ x, const float* __restrict__ pos,
    const unsigned* __restrict__ agg,
    const float* __restrict__ Wx, const float* __restrict__ Wp,
    const float* __restrict__ Wout,
    float* __restrict__ out_sup, float* __restrict__ ctx_part)
{
    const int lane = threadIdx.x & 63;
    const int wv   = threadIdx.x >> 6;
    const int c0 = lane * 2, c1 = c0 + 1;

    float wxa[DXI], wxb_[DXI];
#pragma unroll
    for (int k = 0; k < DXI; ++k) { wxa[k] = Wx[k * H + c0]; wxb_[k] = Wx[k * H + c1]; }
    const float wp00 = Wp[c0], wp01 = Wp[H + c0];
    const float wp10 = Wp[c1], wp11 = Wp[H + c1];
    const float woa0 = Wout[c0 * 3], woa1 = Wout[c0 * 3 + 1], woa2 = Wout[c0 * 3 + 2];
    const float wob0 = Wout[c1 * 3], wob1 = Wout[c1 * 3 + 1], wob2 = Wout[c1 * 3 + 2];

    float ctx0 = 0.f, ctx1 = 0.f;

    for (int n = blockIdx.x * 4 + wv; n < NNODES; n += gridDim.x * 4) {
        const unsigned ag = agg[(size_t)n * 64 + lane];
        const float* xr = x + (size_t)n * DXI;
        const float px = pos[(size_t)n * 3], py = pos[(size_t)n * 3 + 1];
        float a0 = fmaf(wp00, px, wp01 * py);
        float a1 = fmaf(wp10, px, wp11 * py);
#pragma unroll
        for (int k = 0; k < DXI; ++k) {
            const float xv = xr[k];
            a0 = fmaf(xv, wxa[k], a0);
            a1 = fmaf(xv, wxb_[k], a1);
        }
        const float h0 = fast_tanh(fast_tanh(a0) + __uint_as_float(ag << 16));
        const float h1 = fast_tanh(fast_tanh(a1) + __uint_as_float(ag & 0xffff0000u));
        ctx0 += h0; ctx1 += h1;

        float p0 = fmaf(h0, woa0, h1 * wob0);
        float p1 = fmaf(h0, woa1, h1 * wob1);
        float p2 = fmaf(h0, woa2, h1 * wob2);
#pragma unroll
        for (int m = 32; m; m >>= 1) {
            p0 += __shfl_xor(p0, m);
            p1 += __shfl_xor(p1, m);
            p2 += __shfl_xor(p2, m);
        }
        if (lane == 0) {
            out_sup[(size_t)n * 3 + 0] = p0;
            out_sup[(size_t)n * 3 + 1] = p1;
            out_sup[(size_t)n * 3 + 2] = p2;
        }
    }

    __shared__ float part[4][H];
    part[wv][c0] = ctx0;
    part[wv][c1] = ctx1;
    __syncthreads();
    if (threadIdx.x < H) {
        const int ch = threadIdx.x;
        ctx_part[(size_t)blockIdx.x * H + ch] =
            part[0][ch] + part[1][ch] + part[2][ch] + part[3][ch];
    }
}

// ---------------------------------------------------------------------------
// ctx finalize: sum per-block partial rows, then tab rows.
// ---------------------------------------------------------------------------
__global__ __launch_bounds__(128) void ctx_kernel(
    const float* __restrict__ ctx_part, const float* __restrict__ W1,
    const float* __restrict__ b1, float* __restrict__ tab)
{
    __shared__ float ctx[H];
    const int ch = threadIdx.x;
    float s0 = 0.f, s1 = 0.f, s2 = 0.f, s3 = 0.f;
#pragma unroll 4
    for (int b = 0; b < NODE_BLOCKS; b += 4) {
        s0 += ctx_part[(size_t)(b + 0) * H + ch];
        s1 += ctx_part[(size_t)(b + 1) * H + ch];
        s2 += ctx_part[(size_t)(b + 2) * H + ch];
        s3 += ctx_part[(size_t)(b + 3) * H + ch];
    }
    ctx[ch] = (s0 + s1 + s2 + s3) * (1.0f / (float)NNODES);
    __syncthreads();
    float acc = b1[ch];
    for (int k = 0; k < H; ++k) acc = fmaf(ctx[k], W1[(size_t)(2 + k) * H + ch], acc);
    const float A0 = W1[ch], A1 = W1[H + ch];
    tab[ch * 8 + 0] = A0;
    tab[ch * 8 + 1] = A1;
    tab[ch * 8 + 2] = acc;
    tab[ch * 8 + 3] = A0 * A0;
    tab[ch * 8 + 4] = A1 * A1;
    tab[ch * 8 + 5] = 0.f;
    tab[ch * 8 + 6] = 0.f;
    tab[ch * 8 + 7] = 0.f;
}

// ---------------------------------------------------------------------------
// Sampling kernel (MFMA): block = 32 points, 256 thr = 4 waves.
// 5 GEMMs C_q = A_q x W2 share one B (bf16 W2^T in LDS). Epilogue:
// tanh/physics in-register, shfl j-reduce, LDS cross-wave combine, direct
// out writes (incl. boundary residuals).
// ---------------------------------------------------------------------------
__global__ __launch_bounds__(256, 2) void samp_mfma_kernel(
    const float* __restrict__ dom, const float* __restrict__ bnd,
    const int* __restrict__ bidx,
    const float* __restrict__ x, const float* __restrict__ xmask,
    const float* __restrict__ tab,
    const float* __restrict__ W2, const float* __restrict__ b2,
    const float* __restrict__ W3, float* __restrict__ out)
{
    __shared__ __attribute__((aligned(16))) short Bt[128 * KPAD];     // 34816 B
    __shared__ __attribute__((aligned(16))) short Alds[5 * A_STRIDE]; // 43520 B
    __shared__ __attribute__((aligned(16))) float red[32][13];        // 1664 B

    const int tid = threadIdx.x;
    const int blk = blockIdx.x;

    // phase 0a: W2 -> Bt (transposed, bf16)
    for (int i = tid; i < H * H; i += 256) {
        const int k = i >> 7, n = i & 127;
        Bt[n * KPAD + k] = to_bf16(W2[i]);
    }

    // phase 0b: generate 5 A matrices for this block's 32 points
    for (int idx = tid; idx < 32 * 64; idx += 256) {
        const int pl = idx >> 6;
        const int k0 = (idx & 63) * 2;
        const int p  = blk * 32 + pl;
        float spx, spy;
        if (p < NDOM) { spx = dom[(size_t)p * 2];          spy = dom[(size_t)p * 2 + 1]; }
        else          { spx = bnd[(size_t)(p - NDOM) * 2]; spy = bnd[(size_t)(p - NDOM) * 2 + 1]; }
        float v[2][5];
#pragma unroll
        for (int kk = 0; kk < 2; ++kk) {
            const int k = k0 + kk;
            const float4 t4 = *(const float4*)(tab + (size_t)k * 8);
            const float A1s = tab[(size_t)k * 8 + 4];
            const float A0 = t4.x, A1 = t4.y, cc = t4.z, A0s = t4.w;
            const float a1 = fmaf(spx, A0, fmaf(spy, A1, cc));
            const float e  = __builtin_amdgcn_exp2f(a1 * 2.88539008f);
            const float h1 = fmaf(-2.f, __builtin_amdgcn_rcpf(e + 1.f), 1.f);
            const float t1 = fmaf(-h1, h1, 1.f);
            const float m2 = -2.f * h1 * t1;
            v[kk][0] = h1;
            v[kk][1] = t1 * A0;
            v[kk][2] = t1 * A1;
            v[kk][3] = m2 * A0s;
            v[kk][4] = m2 * A1s;
        }
        const int base = pl * KPAD + k0;
#pragma unroll
        for (int q = 0; q < 5; ++q)
            *(unsigned*)&Alds[q * A_STRIDE + base] = pack_bf16(v[0][q], v[1][q]);
    }
    __syncthreads();

    // phase 1: MFMA. wave = (pt, jh): 16 points x 64 j.
    const int lane = tid & 63;
    const int wv = tid >> 6;
    const int pt = wv >> 1;
    const int jh = wv & 1;
    const int ln = lane & 15;
    const int hi = lane >> 4;

    f32x4 acc[4][5];
#pragma unroll
    for (int nt = 0; nt < 4; ++nt)
#pragma unroll
        for (int q = 0; q < 5; ++q)
            acc[nt][q] = (f32x4){0.f, 0.f, 0.f, 0.f};

#pragma unroll
    for (int kc = 0; kc < 4; ++kc) {
        short8 af[5];
#pragma unroll
        for (int q = 0; q < 5; ++q)
            af[q] = *(const short8*)&Alds[q * A_STRIDE + (pt * 16 + ln) * KPAD + kc * 32 + hi * 8];
        short8 bfr[4];
#pragma unroll
        for (int nt = 0; nt < 4; ++nt)
            bfr[nt] = *(const short8*)&Bt[(jh * 64 + nt * 16 + ln) * KPAD + kc * 32 + hi * 8];
#pragma unroll
        for (int nt = 0; nt < 4; ++nt)
#pragma unroll
            for (int q = 0; q < 5; ++q)
                acc[nt][q] = __builtin_amdgcn_mfma_f32_16x16x32_bf16(af[q], bfr[nt], acc[nt][q], 0, 0, 0);
    }

    // phase 2: epilogue. lane holds (j = jh*64+nt*16+ln, 4 points via regs).
    float w30[4], w31[4], w32[4], b2j[4];
#pragma unroll
    for (int nt = 0; nt < 4; ++nt) {
        const int j = jh * 64 + nt * 16 + ln;
        w30[nt] = W3[j * 3];
        w31[nt] = W3[j * 3 + 1];
        w32[nt] = W3[j * 3 + 2];
        b2j[nt] = b2[j];
    }

    float rr[4][13];
#pragma unroll
    for (int i = 0; i < 4; ++i)
#pragma unroll
        for (int c = 0; c < 13; ++c) rr[i][c] = 0.f;

#pragma unroll
    for (int i = 0; i < 4; ++i) {
#pragma unroll
        for (int nt = 0; nt < 4; ++nt) {
            const float a2v  = acc[nt][0][i] + b2j[nt];
            const float d2xv = acc[nt][1][i];
            const float d2yv = acc[nt][2][i];
            const float exxv = acc[nt][3][i];
            const float eyyv = acc[nt][4][i];
            const float h2 = fast_tanh(a2v);
            const float t2 = fmaf(-h2, h2, 1.f);
            const float gx = t2 * d2xv;
            const float gy = t2 * d2yv;
            const float hxx = fmaf(-2.f * h2 * gx, d2xv, t2 * exxv);
            const float hyy = fmaf(-2.f * h2 * gy, d2yv, t2 * eyyv);
            rr[i][0]  = fmaf(h2, w30[nt], rr[i][0]);
            rr[i][1]  = fmaf(h2, w31[nt], rr[i][1]);
            rr[i][2]  = fmaf(h2, w32[nt], rr[i][2]);
            rr[i][3]  = fmaf(gx, w30[nt], rr[i][3]);
            rr[i][4]  = fmaf(gx, w31[nt], rr[i][4]);
            rr[i][5]  = fmaf(gx, w32[nt], rr[i][5]);
            rr[i][6]  = fmaf(gy, w30[nt], rr[i][6]);
            rr[i][7]  = fmaf(gy, w31[nt], rr[i][7]);
            rr[i][8]  = fmaf(gy, w32[nt], rr[i][8]);
            rr[i][9]  = fmaf(hxx, w30[nt], rr[i][9]);
            rr[i][10] = fmaf(hxx, w31[nt], rr[i][10]);
            rr[i][11] = fmaf(hyy, w30[nt], rr[i][11]);
            rr[i][12] = fmaf(hyy, w31[nt], rr[i][12]);
        }
    }

    // reduce over the 16 j-lanes
#pragma unroll
    for (int m = 1; m < 16; m <<= 1)
#pragma unroll
        for (int i = 0; i < 4; ++i)
#pragma unroll
            for (int c = 0; c < 13; ++c)
                rr[i][c] += __shfl_xor(rr[i][c], m);

    if (ln == 0 && jh == 0) {
#pragma unroll
        for (int i = 0; i < 4; ++i) {
            const int pl = pt * 16 + hi * 4 + i;
#pragma unroll
            for (int c = 0; c < 13; ++c) red[pl][c] = rr[i][c];
        }
    }
    __syncthreads();
    if (ln == 0 && jh == 1) {
#pragma unroll
        for (int i = 0; i < 4; ++i) {
            const int pl = pt * 16 + hi * 4 + i;
#pragma unroll
            for (int c = 0; c < 13; ++c) red[pl][c] += rr[i][c];
        }
    }
    __syncthreads();

    // phase 3: physics + writes, one thread per point
    if (tid < 32) {
        const int p = blk * 32 + tid;
        float s[13];
#pragma unroll
        for (int c = 0; c < 13; ++c) s[c] = red[tid][c];
        const float u = s[0], v = s[1], pp = s[2];
        const float ux = s[3], vx = s[4], px = s[5];
        const float uy = s[6], vy = s[7], py = s[8];
        const float uxx = s[9], vxx = s[10], uyy = s[11], vyy = s[12];
        if (p < NDOM) {
            out[CONT_OFF + p] = ux + vy;
            out[MOMX_OFF + p] = fmaf(u, ux, fmaf(v, uy, px)) - (uxx + uyy) * INV_RE;
            out[MOMY_OFF + p] = fmaf(u, vx, fmaf(v, vy, py)) - (vxx + vyy) * INV_RE;
        } else {
            const int i = p - NDOM;
            const int idx = bidx[i];
            const float* xbp = x + (size_t)idx * DXI;
            const float* mm = xmask + (size_t)idx * 6;
            const float tx = xbp[0], ty = xbp[1];
            const float nx = -ty, ny = tx;
            const float r_vt = fabsf(tx * u + ty * v - xbp[2]) * mm[1];
            const float r_vn = fabsf(nx * u + ny * v - xbp[3]) * mm[2];
            const float r_p  = fabsf(pp - xbp[4]) * mm[3];
            const float r_dv = fabsf(nx * ux + ny * vy - xbp[5]) * mm[4];
            const float r_dp = fabsf(nx * px + ny * py - xbp[6]) * mm[5];
            const float c = mm[1] + mm[2] + mm[3] + mm[4] + mm[5];
            out[BND_OFF + i] = (r_vt + r_vn + r_p + r_dv + r_dp) / c;
        }
    }
}

extern "C" void kernel_launch(void* const* d_in, const int* in_sizes, int n_in,
                              void* d_out, int out_size, void* d_ws, size_t ws_size,
                              hipStream_t stream) {
    const float* x     = (const float*)d_in[0];
    const float* xmask = (const float*)d_in[1];
    const int*   eidx  = (const int*)d_in[2];
    const float* eattr = (const float*)d_in[3];
    const float* pos   = (const float*)d_in[4];
    const float* dom   = (const float*)d_in[6];
    const float* bnd   = (const float*)d_in[7];
    const int*   bidx  = (const int*)d_in[8];
    const float* Wx    = (const float*)d_in[9];
    const float* Wp    = (const float*)d_in[10];
    const float* We    = (const float*)d_in[11];
    const float* Wout  = (const float*)d_in[12];
    const float* W1    = (const float*)d_in[13];
    const float* b1    = (const float*)d_in[14];
    const float* W2    = (const float*)d_in[15];
    const float* b2    = (const float*)d_in[16];
    const float* W3    = (const float*)d_in[17];

    float* out = (float*)d_out;

    // workspace layout (16B-aligned sections): total ~48 MB
    int*            counts   = (int*)d_ws;                    // NNODES
    int*            offsets  = counts + NNODES;               // NNODES + 8
    int*            cursor   = offsets + NNODES + 8;          // NNODES
    int*            bsum     = cursor + NNODES;               // 128
    uint2*          csrE     = (uint2*)(bsum + 128);          // NEDGES uint2 (8 MB)
    unsigned short* th       = (unsigned short*)(csrE + NEDGES); // NNODES*64 ushort (12.8 MB)
    unsigned*       agg      = (unsigned*)(th + (size_t)NNODES * 64); // NNODES*64 (25.6 MB)
    float*          ctx_part = (float*)(agg + (size_t)NNODES * 64);   // NODE_BLOCKS*H (512 KB)
    float*          tab      = ctx_part + (size_t)NODE_BLOCKS * H;    // H*8

    (void)hipMemsetAsync(counts, 0, (size_t)NNODES * sizeof(int), stream);

    hist_th_kernel<<<2048, 256, 0, stream>>>(eidx, x, pos, Wx, Wp, counts, th, (uint4*)agg);
    scan1_kernel<<<NSB, 256, 0, stream>>>(counts, offsets, bsum);
    scan2_kernel<<<1, 128, 0, stream>>>(bsum);
    scan3_kernel<<<NSB, 256, 0, stream>>>(offsets, cursor, bsum);
    scatter_kernel<<<8192, 256, 0, stream>>>(eidx, eattr, cursor, csrE);
    seg_edge_kernel<<<(NRUNS + 3) / 4, 256, 0, stream>>>(csrE, th, We, agg);
    node_kernel<<<NODE_BLOCKS, 256, 0, stream>>>(x, pos, agg, Wx, Wp, Wout, out, ctx_part);
    ctx_kernel<<<1, H, 0, stream>>>(ctx_part, W1, b1, tab);
    samp_mfma_kernel<<<NPTS / 32, 256, 0, stream>>>(dom, bnd, bidx, x, xmask, tab, W2, b2, W3, out);
}

// Round 25
// 247.421 us; speedup vs baseline: 1.1051x; 1.0032x over previous
//
#include <hip/hip_runtime.h>
#include <hip/hip_fp8.h>
#include <math.h>

#define H 128
#define DXI 8
#define NNODES 100000
#define NEDGES 1000000
#define NRUNS (NEDGES / 64)
#define NDOM 32768
#define NBND 8192
#define NPTS (NDOM + NBND)
#define INV_RE 1.45e-05f
#define NODE_BLOCKS 1024
#define NPR (NNODES / 8)        // dst range size per partition = 12500

#define NSB ((NNODES + 1023) / 1024)   // scan blocks (1024 elems each) = 98

// d_out layout (floats): out_sup[300000] | continuity[32768] | momx[32768] | momy[32768] | boundary[8192]
#define CONT_OFF (NNODES * 3)
#define MOMX_OFF (CONT_OFF + NDOM)
#define MOMY_OFF (MOMX_OFF + NDOM)
#define BND_OFF  (MOMY_OFF + NDOM)

#define KPAD 136                 // halves per LDS row (128 + 8 pad -> 272B, 16B mult)
#define A_STRIDE (32 * KPAD)     // halves per A matrix

typedef __attribute__((ext_vector_type(8))) short short8;
typedef __attribute__((ext_vector_type(4))) float f32x4;

// fast tanh: 1 - 2/(exp2(2x*log2e)+1). Saturates correctly at +/-inf.
__device__ __forceinline__ float fast_tanh(float x) {
    const float e = __builtin_amdgcn_exp2f(x * 2.88539008f);
    return fmaf(-2.f, __builtin_amdgcn_rcpf(e + 1.f), 1.f);
}

// pack two floats to bf16 pair (RNE), low word = a, high word = b
__device__ __forceinline__ unsigned pack_bf16(float a, float b) {
    unsigned ua = __float_as_uint(a), ub = __float_as_uint(b);
    ua += 0x7fffu + ((ua >> 16) & 1u);
    ub += 0x7fffu + ((ub >> 16) & 1u);
    return (ua >> 16) | (ub & 0xffff0000u);
}

__device__ __forceinline__ short to_bf16(float f) {
    unsigned u = __float_as_uint(f);
    u += 0x7fffu + ((u >> 16) & 1u);
    return (short)(u >> 16);
}

__device__ __forceinline__ float fp8_dec(unsigned b) {
    __hip_fp8_e4m3 d;
    d.__x = (__hip_fp8_storage_t)b;
    return (float)d;
}

// ---------------------------------------------------------------------------
// th table (fp8, 2ch/lane in ushort) + XCD-PRIVATIZED dst histogram +
// agg zero-init (fused). Histogram: one dst sweep; each block atomics into
// copy counts8[blockIdx&7] -> copy stays resident in that XCD's L2 under
// round-robin dispatch, no cross-XCD line ping-pong. scan1 sums the 8 copies.
// ---------------------------------------------------------------------------
__global__ __launch_bounds__(256) void hist_th_kernel(
    const int* __restrict__ eidx, const float* __restrict__ x,
    const float* __restrict__ pos,
    const float* __restrict__ Wx, const float* __restrict__ Wp,
    int* __restrict__ counts8, unsigned short* __restrict__ th,
    uint4* __restrict__ agg4)
{
    const int lane = threadIdx.x & 63;
    const int wv   = threadIdx.x >> 6;
    const int c0 = lane * 2, c1 = c0 + 1;

    // zero agg (overlapped with compute below)
    const int gid = blockIdx.x * 256 + threadIdx.x;
    const uint4 z = make_uint4(0u, 0u, 0u, 0u);
    for (size_t i = gid; i < (size_t)NNODES * 16; i += (size_t)gridDim.x * 256)
        agg4[i] = z;

    float wxa[DXI], wxb_[DXI];
#pragma unroll
    for (int k = 0; k < DXI; ++k) { wxa[k] = Wx[k * H + c0]; wxb_[k] = Wx[k * H + c1]; }
    const float wp00 = Wp[c0], wp01 = Wp[H + c0];
    const float wp10 = Wp[c1], wp11 = Wp[H + c1];

    for (int n = blockIdx.x * 4 + wv; n < NNODES; n += gridDim.x * 4) {
        const float* xr = x + (size_t)n * DXI;
        const float px = pos[(size_t)n * 3], py = pos[(size_t)n * 3 + 1];
        float a0 = fmaf(wp00, px, wp01 * py);
        float a1 = fmaf(wp10, px, wp11 * py);
#pragma unroll
        for (int k = 0; k < DXI; ++k) {
            const float xv = xr[k];
            a0 = fmaf(xv, wxa[k], a0);
            a1 = fmaf(xv, wxb_[k], a1);
        }
        const __hip_fp8_e4m3 q0(fast_tanh(a0));
        const __hip_fp8_e4m3 q1(fast_tanh(a1));
        th[(size_t)n * 64 + lane] =
            (unsigned short)((unsigned)q0.__x | ((unsigned)q1.__x << 8));
    }

    // XCD-local histogram: one sweep of dst; atomics into this XCD's copy
    const int* dst = eidx + NEDGES;
    int* mycnt = counts8 + (size_t)(blockIdx.x & 7) * NNODES;
    for (int e = gid; e < NEDGES; e += gridDim.x * 256)
        atomicAdd(&mycnt[dst[e]], 1);
}

// ---------------------------------------------------------------------------
// CSR build pass 2a: per-block exclusive scan (1024 elems/block), summing
// the 8 XCD-private histogram copies.
// ---------------------------------------------------------------------------
__global__ __launch_bounds__(256) void scan1_kernel(
    const int* __restrict__ counts8, int* __restrict__ excl, int* __restrict__ bsum)
{
    const int tid = threadIdx.x, b = blockIdx.x;
    const int base = b * 1024 + tid * 4;
    int v0 = 0, v1 = 0, v2 = 0, v3 = 0;
    if (base + 3 < NNODES) {
#pragma unroll
        for (int r = 0; r < 8; ++r) {
            const int4 t = *(const int4*)(counts8 + (size_t)r * NNODES + base);
            v0 += t.x; v1 += t.y; v2 += t.z; v3 += t.w;
        }
    } else {
        for (int r = 0; r < 8; ++r) {
            const int* c = counts8 + (size_t)r * NNODES;
            if (base     < NNODES) v0 += c[base];
            if (base + 1 < NNODES) v1 += c[base + 1];
            if (base + 2 < NNODES) v2 += c[base + 2];
            if (base + 3 < NNODES) v3 += c[base + 3];
        }
    }
    const int own = v0 + v1 + v2 + v3;
    int s = own;
    const int lane = tid & 63, wv = tid >> 6;
#pragma unroll
    for (int d = 1; d < 64; d <<= 1) {
        const int t = __shfl_up(s, d);
        if (lane >= d) s += t;
    }
    __shared__ int wsum[4];
    if (lane == 63) wsum[wv] = s;
    __syncthreads();
    int woff = 0;
    for (int w = 0; w < wv; ++w) woff += wsum[w];
    const int e0 = s - own + woff;
    const int e1 = e0 + v0, e2 = e1 + v1, e3 = e2 + v2;
    if (base + 3 < NNODES) {
        *(int4*)(excl + base) = make_int4(e0, e1, e2, e3);
    } else {
        if (base     < NNODES) excl[base]     = e0;
        if (base + 1 < NNODES) excl[base + 1] = e1;
        if (base + 2 < NNODES) excl[base + 2] = e2;
        if (base + 3 < NNODES) excl[base + 3] = e3;
    }
    if (tid == 0) bsum[b] = wsum[0] + wsum[1] + wsum[2] + wsum[3];
}

// ---------------------------------------------------------------------------
// CSR build pass 2b: exclusive scan of block totals (1 block).
// ---------------------------------------------------------------------------
__global__ __launch_bounds__(128) void scan2_kernel(int* __restrict__ bsum)
{
    const int tid = threadIdx.x;
    int v = (tid < NSB) ? bsum[tid] : 0;
    const int own = v;
    const int lane = tid & 63, wv = tid >> 6;
#pragma unroll
    for (int d = 1; d < 64; d <<= 1) {
        const int t = __shfl_up(v, d);
        if (lane >= d) v += t;
    }
    __shared__ int ws2[2];
    if (lane == 63) ws2[wv] = v;
    __syncthreads();
    if (wv == 1) v += ws2[0];
    if (tid < NSB) bsum[tid] = v - own;
}

// ---------------------------------------------------------------------------
// CSR build pass 2c: add block offsets; produce cursor[].
// ---------------------------------------------------------------------------
__global__ __launch_bounds__(256) void scan3_kernel(
    int* __restrict__ offsets, int* __restrict__ cursor, const int* __restrict__ bsum)
{
    const int tid = threadIdx.x, b = blockIdx.x;
    const int base = b * 1024 + tid * 4;
    const int add = bsum[b];
    if (base + 3 < NNODES) {
        int4 t = *(const int4*)(offsets + base);
        t.x += add; t.y += add; t.z += add; t.w += add;
        *(int4*)(offsets + base) = t;
        *(int4*)(cursor + base) = t;
    } else {
        for (int i = 0; i < 4; ++i)
            if (base + i < NNODES) {
                const int t = offsets[base + i] + add;
                offsets[base + i] = t;
                cursor[base + i] = t;
            }
    }
}

// ---------------------------------------------------------------------------
// CSR build pass 3 (range-partitioned strided scatter, 8B packed records):
// block (g = blockIdx>>3, r = blockIdx&7) sweeps the edge stride-set,
// scattering only dsts in range r. Record: 58-bit pack
// {src:17 | dst:17 | fp8 e0,e1,e3} in uint2. Grid 8192 for latency hiding.
// ---------------------------------------------------------------------------
__global__ __launch_bounds__(256) void scatter_kernel(
    const int* __restrict__ eidx, const float* __restrict__ eattr,
    int* __restrict__ cursor, uint2* __restrict__ csrE)
{
    const int* dst = eidx + NEDGES;
    const int G   = gridDim.x >> 3;
    const int g   = blockIdx.x >> 3;
    const int r   = blockIdx.x & 7;
    const int dlo = r * NPR, dhi = dlo + NPR;
    for (int e = g * 256 + threadIdx.x; e < NEDGES; e += G * 256) {
        const int d = dst[e];
        if (d >= dlo && d < dhi) {
            const float4 ea = ((const float4*)eattr)[e];
            const int slot = atomicAdd(&cursor[d], 1);
            const __hip_fp8_e4m3 f0(ea.x), f1(ea.y), f3(ea.w);
            const unsigned long long v =
                (unsigned long long)(unsigned)eidx[e]
              | ((unsigned long long)(unsigned)d << 17)
              | ((unsigned long long)f0.__x << 34)
              | ((unsigned long long)f1.__x << 42)
              | ((unsigned long long)f3.__x << 50);
            csrE[slot] = make_uint2((unsigned)v, (unsigned)(v >> 32));
        }
    }
}

// ---------------------------------------------------------------------------
// Segmented edge kernel: one WAVE per 64-edge dst-sorted run. 8B records;
// coalesced fp8 th-row reads (16-deep batches), readlane broadcast,
// segmented flush to agg[dst] (bf16x2).
// ---------------------------------------------------------------------------
__global__ __launch_bounds__(256) void seg_edge_kernel(
    const uint2* __restrict__ csrE, const unsigned short* __restrict__ th,
    const float* __restrict__ We, unsigned* __restrict__ agg)
{
    const int run = blockIdx.x * 4 + (threadIdx.x >> 6);
    if (run >= NRUNS) return;
    const int lane = threadIdx.x & 63;
    const int c0 = lane * 2, c1 = c0 + 1;

    const float wea0 = We[c0], wea1 = We[H + c0], wea2 = We[2 * H + c0];
    const float web0 = We[c1], web1 = We[H + c1], web2 = We[2 * H + c1];

    const uint2 rec = csrE[(size_t)run * 64 + lane];
    const int mysrc = (int)(rec.x & 0x1FFFFu);
    const int mydst = (int)((rec.x >> 17) | ((rec.y & 3u) << 15));

    float acc0 = 0.f, acc1 = 0.f;
    bool first = true;
    int cur = __builtin_amdgcn_readlane(mydst, 0);

#pragma unroll
    for (int sub = 0; sub < 4; ++sub) {
        unsigned short rowv[16];
#pragma unroll
        for (int t = 0; t < 16; ++t) {
            const int s = __builtin_amdgcn_readlane(mysrc, sub * 16 + t);
            rowv[t] = th[(size_t)s * 64 + lane];
        }
#pragma unroll
        for (int t = 0; t < 16; ++t) {
            const int e = sub * 16 + t;
            const unsigned hi = (unsigned)__builtin_amdgcn_readlane((int)rec.y, e);
            const float e0f = fp8_dec((hi >> 2) & 0xffu);
            const float e1f = fp8_dec((hi >> 10) & 0xffu);
            const float e3f = fp8_dec((hi >> 18) & 0xffu);
            const float th0 = fp8_dec(rowv[t] & 0xffu);
            const float th1 = fp8_dec((unsigned)rowv[t] >> 8);
            const float w0 = fmaf(e0f, wea0, fmaf(e1f, wea1, e3f * wea2));
            const float w1 = fmaf(e0f, web0, fmaf(e1f, web1, e3f * web2));
            acc0 = fmaf(th0, w0, acc0);
            acc1 = fmaf(th1, w1, acc1);

            const int nxt = (e < 63) ? __builtin_amdgcn_readlane(mydst, e + 1) : -1;
            if (nxt != cur) {
                unsigned* p = agg + (size_t)cur * 64 + lane;
                if (first || e == 63) {
                    unsigned old = *p;
                    while (true) {
                        const float g0 = __uint_as_float(old << 16) + acc0;
                        const float g1 = __uint_as_float(old & 0xffff0000u) + acc1;
                        const unsigned nw = pack_bf16(g0, g1);
                        const unsigned prev = atomicCAS(p, old, nw);
                        if (prev == old) break;
                        old = prev;
                    }
                } else {
                    *p = pack_bf16(acc0, acc1);
                }
                acc0 = 0.f; acc1 = 0.f;
                first = false;
                cur = nxt;
            }
        }
    }
}

// ---------------------------------------------------------------------------
// Node kernel: wave per node, 2ch/lane. ctx via LDS reduce + per-block row.
// ---------------------------------------------------------------------------
__global__ __launch_bounds__(256) void node_kernel(
    const float* __restrict__ x, const float* __restrict__ pos,
    const unsigned* __restrict__ agg,
    const float* __restrict__ Wx, const float* __restrict__ Wp,
    const float* __restrict__ Wout,
    float* __restrict__ out_sup, float* __restrict__ ctx_part)
{
    const int lane = threadIdx.x & 63;
    const int wv   = threadIdx.x >> 6;
    const int c0 = lane * 2, c1 = c0 + 1;

    float wxa[DXI], wxb_[DXI];
#pragma unroll
    for (int k = 0; k < DXI; ++k) { wxa[k] = Wx[k * H + c0]; wxb_[k] = Wx[k * H + c1]; }
    const float wp00 = Wp[c0], wp01 = Wp[H + c0];
    const float wp10 = Wp[c1], wp11 = Wp[H + c1];
    const float woa0 = Wout[c0 * 3], woa1 = Wout[c0 * 3 + 1], woa2 = Wout[c0 * 3 + 2];
    const float wob0 = Wout[c1 * 3], wob1 = Wout[c1 * 3 + 1], wob2 = Wout[c1 * 3 + 2];

    float ctx0 = 0.f, ctx1 = 0.f;

    for (int n = blockIdx.x * 4 + wv; n < NNODES; n += gridDim.x * 4) {
        const unsigned ag = agg[(size_t)n * 64 + lane];
        const float* xr = x + (size_t)n * DXI;
        const float px = pos[(size_t)n * 3], py = pos[(size_t)n * 3 + 1];
        float a0 = fmaf(wp00, px, wp01 * py);
        float a1 = fmaf(wp10, px, wp11 * py);
#pragma unroll
        for (int k = 0; k < DXI; ++k) {
            const float xv = xr[k];
            a0 = fmaf(xv, wxa[k], a0);
            a1 = fmaf(xv, wxb_[k], a1);
        }
        const float h0 = fast_tanh(fast_tanh(a0) + __uint_as_float(ag << 16));
        const float h1 = fast_tanh(fast_tanh(a1) + __uint_as_float(ag & 0xffff0000u));
        ctx0 += h0; ctx1 += h1;

        float p0 = fmaf(h0, woa0, h1 * wob0);
        float p1 = fmaf(h0, woa1, h1 * wob1);
        float p2 = fmaf(h0, woa2, h1 * wob2);
#pragma unroll
        for (int m = 32; m; m >>= 1) {
            p0 += __shfl_xor(p0, m);
            p1 += __shfl_xor(p1, m);
            p2 += __shfl_xor(p2, m);
        }
        if (lane == 0) {
            out_sup[(size_t)n * 3 + 0] = p0;
            out_sup[(size_t)n * 3 + 1] = p1;
            out_sup[(size_t)n * 3 + 2] = p2;
        }
    }

    __shared__ float part[4][H];
    part[wv][c0] = ctx0;
    part[wv][c1] = ctx1;
    __syncthreads();
    if (threadIdx.x < H) {
        const int ch = threadIdx.x;
        ctx_part[(size_t)blockIdx.x * H + ch] =
            part[0][ch] + part[1][ch] + part[2][ch] + part[3][ch];
    }
}

// ---------------------------------------------------------------------------
// ctx finalize: sum per-block partial rows, then tab rows.
// ---------------------------------------------------------------------------
__global__ __launch_bounds__(128) void ctx_kernel(
    const float* __restrict__ ctx_part, const float* __restrict__ W1,
    const float* __restrict__ b1, float* __restrict__ tab)
{
    __shared__ float ctx[H];
    const int ch = threadIdx.x;
    float s0 = 0.f, s1 = 0.f, s2 = 0.f, s3 = 0.f;
#pragma unroll 4
    for (int b = 0; b < NODE_BLOCKS; b += 4) {
        s0 += ctx_part[(size_t)(b + 0) * H + ch];
        s1 += ctx_part[(size_t)(b + 1) * H + ch];
        s2 += ctx_part[(size_t)(b + 2) * H + ch];
        s3 += ctx_part[(size_t)(b + 3) * H + ch];
    }
    ctx[ch] = (s0 + s1 + s2 + s3) * (1.0f / (float)NNODES);
    __syncthreads();
    float acc = b1[ch];
    for (int k = 0; k < H; ++k) acc = fmaf(ctx[k], W1[(size_t)(2 + k) * H + ch], acc);
    const float A0 = W1[ch], A1 = W1[H + ch];
    tab[ch * 8 + 0] = A0;
    tab[ch * 8 + 1] = A1;
    tab[ch * 8 + 2] = acc;
    tab[ch * 8 + 3] = A0 * A0;
    tab[ch * 8 + 4] = A1 * A1;
    tab[ch * 8 + 5] = 0.f;
    tab[ch * 8 + 6] = 0.f;
    tab[ch * 8 + 7] = 0.f;
}

// ---------------------------------------------------------------------------
// Sampling kernel (MFMA): block = 32 points, 256 thr = 4 waves.
// 5 GEMMs C_q = A_q x W2 share one B (bf16 W2^T in LDS). Epilogue:
// tanh/physics in-register, shfl j-reduce, LDS cross-wave combine, direct
// out writes (incl. boundary residuals).
// ---------------------------------------------------------------------------
__global__ __launch_bounds__(256, 2) void samp_mfma_kernel(
    const float* __restrict__ dom, const float* __restrict__ bnd,
    const int* __restrict__ bidx,
    const float* __restrict__ x, const float* __restrict__ xmask,
    const float* __restrict__ tab,
    const float* __restrict__ W2, const float* __restrict__ b2,
    const float* __restrict__ W3, float* __restrict__ out)
{
    __shared__ __attribute__((aligned(16))) short Bt[128 * KPAD];     // 34816 B
    __shared__ __attribute__((aligned(16))) short Alds[5 * A_STRIDE]; // 43520 B
    __shared__ __attribute__((aligned(16))) float red[32][13];        // 1664 B

    const int tid = threadIdx.x;
    const int blk = blockIdx.x;

    // phase 0a: W2 -> Bt (transposed, bf16)
    for (int i = tid; i < H * H; i += 256) {
        const int k = i >> 7, n = i & 127;
        Bt[n * KPAD + k] = to_bf16(W2[i]);
    }

    // phase 0b: generate 5 A matrices for this block's 32 points
    for (int idx = tid; idx < 32 * 64; idx += 256) {
        const int pl = idx >> 6;
        const int k0 = (idx & 63) * 2;
        const int p  = blk * 32 + pl;
        float spx, spy;
        if (p < NDOM) { spx = dom[(size_t)p * 2];          spy = dom[(size_t)p * 2 + 1]; }
        else          { spx = bnd[(size_t)(p - NDOM) * 2]; spy = bnd[(size_t)(p - NDOM) * 2 + 1]; }
        float v[2][5];
#pragma unroll
        for (int kk = 0; kk < 2; ++kk) {
            const int k = k0 + kk;
            const float4 t4 = *(const float4*)(tab + (size_t)k * 8);
            const float A1s = tab[(size_t)k * 8 + 4];
            const float A0 = t4.x, A1 = t4.y, cc = t4.z, A0s = t4.w;
            const float a1 = fmaf(spx, A0, fmaf(spy, A1, cc));
            const float e  = __builtin_amdgcn_exp2f(a1 * 2.88539008f);
            const float h1 = fmaf(-2.f, __builtin_amdgcn_rcpf(e + 1.f), 1.f);
            const float t1 = fmaf(-h1, h1, 1.f);
            const float m2 = -2.f * h1 * t1;
            v[kk][0] = h1;
            v[kk][1] = t1 * A0;
            v[kk][2] = t1 * A1;
            v[kk][3] = m2 * A0s;
            v[kk][4] = m2 * A1s;
        }
        const int base = pl * KPAD + k0;
#pragma unroll
        for (int q = 0; q < 5; ++q)
            *(unsigned*)&Alds[q * A_STRIDE + base] = pack_bf16(v[0][q], v[1][q]);
    }
    __syncthreads();

    // phase 1: MFMA. wave = (pt, jh): 16 points x 64 j.
    const int lane = tid & 63;
    const int wv = tid >> 6;
    const int pt = wv >> 1;
    const int jh = wv & 1;
    const int ln = lane & 15;
    const int hi = lane >> 4;

    f32x4 acc[4][5];
#pragma unroll
    for (int nt = 0; nt < 4; ++nt)
#pragma unroll
        for (int q = 0; q < 5; ++q)
            acc[nt][q] = (f32x4){0.f, 0.f, 0.f, 0.f};

#pragma unroll
    for (int kc = 0; kc < 4; ++kc) {
        short8 af[5];
#pragma unroll
        for (int q = 0; q < 5; ++q)
            af[q] = *(const short8*)&Alds[q * A_STRIDE + (pt * 16 + ln) * KPAD + kc * 32 + hi * 8];
        short8 bfr[4];
#pragma unroll
        for (int nt = 0; nt < 4; ++nt)
            bfr[nt] = *(const short8*)&Bt[(jh * 64 + nt * 16 + ln) * KPAD + kc * 32 + hi * 8];
#pragma unroll
        for (int nt = 0; nt < 4; ++nt)
#pragma unroll
            for (int q = 0; q < 5; ++q)
                acc[nt][q] = __builtin_amdgcn_mfma_f32_16x16x32_bf16(af[q], bfr[nt], acc[nt][q], 0, 0, 0);
    }

    // phase 2: epilogue. lane holds (j = jh*64+nt*16+ln, 4 points via regs).
    float w30[4], w31[4], w32[4], b2j[4];
#pragma unroll
    for (int nt = 0; nt < 4; ++nt) {
        const int j = jh * 64 + nt * 16 + ln;
        w30[nt] = W3[j * 3];
        w31[nt] = W3[j * 3 + 1];
        w32[nt] = W3[j * 3 + 2];
        b2j[nt] = b2[j];
    }

    float rr[4][13];
#pragma unroll
    for (int i = 0; i < 4; ++i)
#pragma unroll
        for (int c = 0; c < 13; ++c) rr[i][c] = 0.f;

#pragma unroll
    for (int i = 0; i < 4; ++i) {
#pragma unroll
        for (int nt = 0; nt < 4; ++nt) {
            const float a2v  = acc[nt][0][i] + b2j[nt];
            const float d2xv = acc[nt][1][i];
            const float d2yv = acc[nt][2][i];
            const float exxv = acc[nt][3][i];
            const float eyyv = acc[nt][4][i];
            const float h2 = fast_tanh(a2v);
            const float t2 = fmaf(-h2, h2, 1.f);
            const float gx = t2 * d2xv;
            const float gy = t2 * d2yv;
            const float hxx = fmaf(-2.f * h2 * gx, d2xv, t2 * exxv);
            const float hyy = fmaf(-2.f * h2 * gy, d2yv, t2 * eyyv);
            rr[i][0]  = fmaf(h2, w30[nt], rr[i][0]);
            rr[i][1]  = fmaf(h2, w31[nt], rr[i][1]);
            rr[i][2]  = fmaf(h2, w32[nt], rr[i][2]);
            rr[i][3]  = fmaf(gx, w30[nt], rr[i][3]);
            rr[i][4]  = fmaf(gx, w31[nt], rr[i][4]);
            rr[i][5]  = fmaf(gx, w32[nt], rr[i][5]);
            rr[i][6]  = fmaf(gy, w30[nt], rr[i][6]);
            rr[i][7]  = fmaf(gy, w31[nt], rr[i][7]);
            rr[i][8]  = fmaf(gy, w32[nt], rr[i][8]);
            rr[i][9]  = fmaf(hxx, w30[nt], rr[i][9]);
            rr[i][10] = fmaf(hxx, w31[nt], rr[i][10]);
            rr[i][11] = fmaf(hyy, w30[nt], rr[i][11]);
            rr[i][12] = fmaf(hyy, w31[nt], rr[i][12]);
        }
    }

    // reduce over the 16 j-lanes
#pragma unroll
    for (int m = 1; m < 16; m <<= 1)
#pragma unroll
        for (int i = 0; i < 4; ++i)
#pragma unroll
            for (int c = 0; c < 13; ++c)
                rr[i][c] += __shfl_xor(rr[i][c], m);

    if (ln == 0 && jh == 0) {
#pragma unroll
        for (int i = 0; i < 4; ++i) {
            const int pl = pt * 16 + hi * 4 + i;
#pragma unroll
            for (int c = 0; c < 13; ++c) red[pl][c] = rr[i][c];
        }
    }
    __syncthreads();
    if (ln == 0 && jh == 1) {
#pragma unroll
        for (int i = 0; i < 4; ++i) {
            const int pl = pt * 16 + hi * 4 + i;
#pragma unroll
            for (int c = 0; c < 13; ++c) red[pl][c] += rr[i][c];
        }
    }
    __syncthreads();

    // phase 3: physics + writes, one thread per point
    if (tid < 32) {
        const int p = blk * 32 + tid;
        float s[13];
#pragma unroll
        for (int c = 0; c < 13; ++c) s[c] = red[tid][c];
        const float u = s[0], v = s[1], pp = s[2];
        const float ux = s[3], vx = s[4], px = s[5];
        const float uy = s[6], vy = s[7], py = s[8];
        const float uxx = s[9], vxx = s[10], uyy = s[11], vyy = s[12];
        if (p < NDOM) {
            out[CONT_OFF + p] = ux + vy;
            out[MOMX_OFF + p] = fmaf(u, ux, fmaf(v, uy, px)) - (uxx + uyy) * INV_RE;
            out[MOMY_OFF + p] = fmaf(u, vx, fmaf(v, vy, py)) - (vxx + vyy) * INV_RE;
        } else {
            const int i = p - NDOM;
            const int idx = bidx[i];
            const float* xbp = x + (size_t)idx * DXI;
            const float* mm = xmask + (size_t)idx * 6;
            const float tx = xbp[0], ty = xbp[1];
            const float nx = -ty, ny = tx;
            const float r_vt = fabsf(tx * u + ty * v - xbp[2]) * mm[1];
            const float r_vn = fabsf(nx * u + ny * v - xbp[3]) * mm[2];
            const float r_p  = fabsf(pp - xbp[4]) * mm[3];
            const float r_dv = fabsf(nx * ux + ny * vy - xbp[5]) * mm[4];
            const float r_dp = fabsf(nx * px + ny * py - xbp[6]) * mm[5];
            const float c = mm[1] + mm[2] + mm[3] + mm[4] + mm[5];
            out[BND_OFF + i] = (r_vt + r_vn + r_p + r_dv + r_dp) / c;
        }
    }
}

extern "C" void kernel_launch(void* const* d_in, const int* in_sizes, int n_in,
                              void* d_out, int out_size, void* d_ws, size_t ws_size,
                              hipStream_t stream) {
    const float* x     = (const float*)d_in[0];
    const float* xmask = (const float*)d_in[1];
    const int*   eidx  = (const int*)d_in[2];
    const float* eattr = (const float*)d_in[3];
    const float* pos   = (const float*)d_in[4];
    const float* dom   = (const float*)d_in[6];
    const float* bnd   = (const float*)d_in[7];
    const int*   bidx  = (const int*)d_in[8];
    const float* Wx    = (const float*)d_in[9];
    const float* Wp    = (const float*)d_in[10];
    const float* We    = (const float*)d_in[11];
    const float* Wout  = (const float*)d_in[12];
    const float* W1    = (const float*)d_in[13];
    const float* b1    = (const float*)d_in[14];
    const float* W2    = (const float*)d_in[15];
    const float* b2    = (const float*)d_in[16];
    const float* W3    = (const float*)d_in[17];

    float* out = (float*)d_out;

    // workspace layout (16B-aligned sections): total ~51 MB
    int*            counts8  = (int*)d_ws;                    // 8*NNODES (3.2 MB)
    int*            offsets  = counts8 + 8 * NNODES;          // NNODES + 8
    int*            cursor   = offsets + NNODES + 8;          // NNODES
    int*            bsum     = cursor + NNODES;               // 128
    uint2*          csrE     = (uint2*)(bsum + 128);          // NEDGES uint2 (8 MB)
    unsigned short* th       = (unsigned short*)(csrE + NEDGES); // NNODES*64 ushort (12.8 MB)
    unsigned*       agg      = (unsigned*)(th + (size_t)NNODES * 64); // NNODES*64 (25.6 MB)
    float*          ctx_part = (float*)(agg + (size_t)NNODES * 64);   // NODE_BLOCKS*H (512 KB)
    float*          tab      = ctx_part + (size_t)NODE_BLOCKS * H;    // H*8

    (void)hipMemsetAsync(counts8, 0, (size_t)8 * NNODES * sizeof(int), stream);

    hist_th_kernel<<<2048, 256, 0, stream>>>(eidx, x, pos, Wx, Wp, counts8, th, (uint4*)agg);
    scan1_kernel<<<NSB, 256, 0, stream>>>(counts8, offsets, bsum);
    scan2_kernel<<<1, 128, 0, stream>>>(bsum);
    scan3_kernel<<<NSB, 256, 0, stream>>>(offsets, cursor, bsum);
    scatter_kernel<<<8192, 256, 0, stream>>>(eidx, eattr, cursor, csrE);
    seg_edge_kernel<<<(NRUNS + 3) / 4, 256, 0, stream>>>(csrE, th, We, agg);
    node_kernel<<<NODE_BLOCKS, 256, 0, stream>>>(x, pos, agg, Wx, Wp, Wout, out, ctx_part);
    ctx_kernel<<<1, H, 0, stream>>>(ctx_part, W1, b1, tab);
    samp_mfma_kernel<<<NPTS / 32, 256, 0, stream>>>(dom, bnd, bidx, x, xmask, tab, W2, b2, W3, out);
}

// Round 26
// 246.109 us; speedup vs baseline: 1.1110x; 1.0053x over previous
//
#include <hip/hip_runtime.h>
#include <hip/hip_fp8.h>
#include <math.h>

#define H 128
#define DXI 8
#define NNODES 100000
#define NEDGES 1000000
#define NRUNS (NEDGES / 64)
#define NDOM 32768
#define NBND 8192
#define NPTS (NDOM + NBND)
#define INV_RE 1.45e-05f
#define NODE_BLOCKS 1024
#define NPR (NNODES / 8)        // dst range size per partition = 12500

#define NSB ((NNODES + 1023) / 1024)   // scan blocks (1024 elems each) = 98

// d_out layout (floats): out_sup[300000] | continuity[32768] | momx[32768] | momy[32768] | boundary[8192]
#define CONT_OFF (NNODES * 3)
#define MOMX_OFF (CONT_OFF + NDOM)
#define MOMY_OFF (MOMX_OFF + NDOM)
#define BND_OFF  (MOMY_OFF + NDOM)

#define KPAD 136                 // halves per LDS row (128 + 8 pad -> 272B, 16B mult)
#define A_STRIDE (32 * KPAD)     // halves per A matrix

typedef __attribute__((ext_vector_type(8))) short short8;
typedef __attribute__((ext_vector_type(4))) float f32x4;

// fast tanh: 1 - 2/(exp2(2x*log2e)+1). Saturates correctly at +/-inf.
__device__ __forceinline__ float fast_tanh(float x) {
    const float e = __builtin_amdgcn_exp2f(x * 2.88539008f);
    return fmaf(-2.f, __builtin_amdgcn_rcpf(e + 1.f), 1.f);
}

// pack two floats to bf16 pair (RNE), low word = a, high word = b
__device__ __forceinline__ unsigned pack_bf16(float a, float b) {
    unsigned ua = __float_as_uint(a), ub = __float_as_uint(b);
    ua += 0x7fffu + ((ua >> 16) & 1u);
    ub += 0x7fffu + ((ub >> 16) & 1u);
    return (ua >> 16) | (ub & 0xffff0000u);
}

__device__ __forceinline__ short to_bf16(float f) {
    unsigned u = __float_as_uint(f);
    u += 0x7fffu + ((u >> 16) & 1u);
    return (short)(u >> 16);
}

__device__ __forceinline__ float fp8_dec(unsigned b) {
    __hip_fp8_e4m3 d;
    d.__x = (__hip_fp8_storage_t)b;
    return (float)d;
}

// ---------------------------------------------------------------------------
// th table (fp8, 2ch/lane) + XCD-privatized dst histogram + agg zero-init
// (fused). th loop processes TWO nodes per wave-iteration: two independent
// load->MLP->tanh->fp8 chains in flight (2x ILP over the broadcast-load
// latency that bounds this kernel).
// ---------------------------------------------------------------------------
__global__ __launch_bounds__(256) void hist_th_kernel(
    const int* __restrict__ eidx, const float* __restrict__ x,
    const float* __restrict__ pos,
    const float* __restrict__ Wx, const float* __restrict__ Wp,
    int* __restrict__ counts8, unsigned short* __restrict__ th,
    uint4* __restrict__ agg4)
{
    const int lane = threadIdx.x & 63;
    const int wv   = threadIdx.x >> 6;
    const int c0 = lane * 2, c1 = c0 + 1;

    // zero agg (overlapped with compute below)
    const int gid = blockIdx.x * 256 + threadIdx.x;
    const uint4 z = make_uint4(0u, 0u, 0u, 0u);
    for (size_t i = gid; i < (size_t)NNODES * 16; i += (size_t)gridDim.x * 256)
        agg4[i] = z;

    float wxa[DXI], wxb_[DXI];
#pragma unroll
    for (int k = 0; k < DXI; ++k) { wxa[k] = Wx[k * H + c0]; wxb_[k] = Wx[k * H + c1]; }
    const float wp00 = Wp[c0], wp01 = Wp[H + c0];
    const float wp10 = Wp[c1], wp11 = Wp[H + c1];

    // two nodes per wave-iteration (independent chains for ILP/MLP)
    for (int n = blockIdx.x * 8 + wv * 2; n < NNODES; n += gridDim.x * 8) {
        const int nB = n + 1;
        const bool hasB = (nB < NNODES);

        const float* xrA = x + (size_t)n * DXI;
        const float pxA = pos[(size_t)n * 3], pyA = pos[(size_t)n * 3 + 1];
        const float* xrB = xrA + DXI;
        const float pxB = hasB ? pos[(size_t)nB * 3]     : 0.f;
        const float pyB = hasB ? pos[(size_t)nB * 3 + 1] : 0.f;

        float a0A = fmaf(wp00, pxA, wp01 * pyA);
        float a1A = fmaf(wp10, pxA, wp11 * pyA);
        float a0B = fmaf(wp00, pxB, wp01 * pyB);
        float a1B = fmaf(wp10, pxB, wp11 * pyB);
#pragma unroll
        for (int k = 0; k < DXI; ++k) {
            const float xvA = xrA[k];
            const float xvB = hasB ? xrB[k] : 0.f;
            a0A = fmaf(xvA, wxa[k], a0A);
            a1A = fmaf(xvA, wxb_[k], a1A);
            a0B = fmaf(xvB, wxa[k], a0B);
            a1B = fmaf(xvB, wxb_[k], a1B);
        }
        const __hip_fp8_e4m3 q0A(fast_tanh(a0A));
        const __hip_fp8_e4m3 q1A(fast_tanh(a1A));
        th[(size_t)n * 64 + lane] =
            (unsigned short)((unsigned)q0A.__x | ((unsigned)q1A.__x << 8));
        if (hasB) {
            const __hip_fp8_e4m3 q0B(fast_tanh(a0B));
            const __hip_fp8_e4m3 q1B(fast_tanh(a1B));
            th[(size_t)nB * 64 + lane] =
                (unsigned short)((unsigned)q0B.__x | ((unsigned)q1B.__x << 8));
        }
    }

    // XCD-local histogram: one sweep of dst; atomics into this XCD's copy
    const int* dst = eidx + NEDGES;
    int* mycnt = counts8 + (size_t)(blockIdx.x & 7) * NNODES;
    for (int e = gid; e < NEDGES; e += gridDim.x * 256)
        atomicAdd(&mycnt[dst[e]], 1);
}

// ---------------------------------------------------------------------------
// CSR build pass 2a: per-block exclusive scan (1024 elems/block), summing
// the 8 XCD-private histogram copies.
// ---------------------------------------------------------------------------
__global__ __launch_bounds__(256) void scan1_kernel(
    const int* __restrict__ counts8, int* __restrict__ excl, int* __restrict__ bsum)
{
    const int tid = threadIdx.x, b = blockIdx.x;
    const int base = b * 1024 + tid * 4;
    int v0 = 0, v1 = 0, v2 = 0, v3 = 0;
    if (base + 3 < NNODES) {
#pragma unroll
        for (int r = 0; r < 8; ++r) {
            const int4 t = *(const int4*)(counts8 + (size_t)r * NNODES + base);
            v0 += t.x; v1 += t.y; v2 += t.z; v3 += t.w;
        }
    } else {
        for (int r = 0; r < 8; ++r) {
            const int* c = counts8 + (size_t)r * NNODES;
            if (base     < NNODES) v0 += c[base];
            if (base + 1 < NNODES) v1 += c[base + 1];
            if (base + 2 < NNODES) v2 += c[base + 2];
            if (base + 3 < NNODES) v3 += c[base + 3];
        }
    }
    const int own = v0 + v1 + v2 + v3;
    int s = own;
    const int lane = tid & 63, wv = tid >> 6;
#pragma unroll
    for (int d = 1; d < 64; d <<= 1) {
        const int t = __shfl_up(s, d);
        if (lane >= d) s += t;
    }
    __shared__ int wsum[4];
    if (lane == 63) wsum[wv] = s;
    __syncthreads();
    int woff = 0;
    for (int w = 0; w < wv; ++w) woff += wsum[w];
    const int e0 = s - own + woff;
    const int e1 = e0 + v0, e2 = e1 + v1, e3 = e2 + v2;
    if (base + 3 < NNODES) {
        *(int4*)(excl + base) = make_int4(e0, e1, e2, e3);
    } else {
        if (base     < NNODES) excl[base]     = e0;
        if (base + 1 < NNODES) excl[base + 1] = e1;
        if (base + 2 < NNODES) excl[base + 2] = e2;
        if (base + 3 < NNODES) excl[base + 3] = e3;
    }
    if (tid == 0) bsum[b] = wsum[0] + wsum[1] + wsum[2] + wsum[3];
}

// ---------------------------------------------------------------------------
// CSR build pass 2b: exclusive scan of block totals (1 block).
// ---------------------------------------------------------------------------
__global__ __launch_bounds__(128) void scan2_kernel(int* __restrict__ bsum)
{
    const int tid = threadIdx.x;
    int v = (tid < NSB) ? bsum[tid] : 0;
    const int own = v;
    const int lane = tid & 63, wv = tid >> 6;
#pragma unroll
    for (int d = 1; d < 64; d <<= 1) {
        const int t = __shfl_up(v, d);
        if (lane >= d) v += t;
    }
    __shared__ int ws2[2];
    if (lane == 63) ws2[wv] = v;
    __syncthreads();
    if (wv == 1) v += ws2[0];
    if (tid < NSB) bsum[tid] = v - own;
}

// ---------------------------------------------------------------------------
// CSR build pass 2c: add block offsets; produce cursor[].
// ---------------------------------------------------------------------------
__global__ __launch_bounds__(256) void scan3_kernel(
    int* __restrict__ offsets, int* __restrict__ cursor, const int* __restrict__ bsum)
{
    const int tid = threadIdx.x, b = blockIdx.x;
    const int base = b * 1024 + tid * 4;
    const int add = bsum[b];
    if (base + 3 < NNODES) {
        int4 t = *(const int4*)(offsets + base);
        t.x += add; t.y += add; t.z += add; t.w += add;
        *(int4*)(offsets + base) = t;
        *(int4*)(cursor + base) = t;
    } else {
        for (int i = 0; i < 4; ++i)
            if (base + i < NNODES) {
                const int t = offsets[base + i] + add;
                offsets[base + i] = t;
                cursor[base + i] = t;
            }
    }
}

// ---------------------------------------------------------------------------
// CSR build pass 3 (range-partitioned strided scatter, 8B packed records):
// block (g = blockIdx>>3, r = blockIdx&7) sweeps the edge stride-set,
// scattering only dsts in range r. Record: 58-bit pack
// {src:17 | dst:17 | fp8 e0,e1,e3} in uint2. Grid 8192 for latency hiding.
// ---------------------------------------------------------------------------
__global__ __launch_bounds__(256) void scatter_kernel(
    const int* __restrict__ eidx, const float* __restrict__ eattr,
    int* __restrict__ cursor, uint2* __restrict__ csrE)
{
    const int* dst = eidx + NEDGES;
    const int G   = gridDim.x >> 3;
    const int g   = blockIdx.x >> 3;
    const int r   = blockIdx.x & 7;
    const int dlo = r * NPR, dhi = dlo + NPR;
    for (int e = g * 256 + threadIdx.x; e < NEDGES; e += G * 256) {
        const int d = dst[e];
        if (d >= dlo && d < dhi) {
            const float4 ea = ((const float4*)eattr)[e];
            const int slot = atomicAdd(&cursor[d], 1);
            const __hip_fp8_e4m3 f0(ea.x), f1(ea.y), f3(ea.w);
            const unsigned long long v =
                (unsigned long long)(unsigned)eidx[e]
              | ((unsigned long long)(unsigned)d << 17)
              | ((unsigned long long)f0.__x << 34)
              | ((unsigned long long)f1.__x << 42)
              | ((unsigned long long)f3.__x << 50);
            csrE[slot] = make_uint2((unsigned)v, (unsigned)(v >> 32));
        }
    }
}

// ---------------------------------------------------------------------------
// Segmented edge kernel: one WAVE per 64-edge dst-sorted run. 8B records;
// coalesced fp8 th-row reads (16-deep batches), readlane broadcast,
// segmented flush to agg[dst] (bf16x2).
// ---------------------------------------------------------------------------
__global__ __launch_bounds__(256) void seg_edge_kernel(
    const uint2* __restrict__ csrE, const unsigned short* __restrict__ th,
    const float* __restrict__ We, unsigned* __restrict__ agg)
{
    const int run = blockIdx.x * 4 + (threadIdx.x >> 6);
    if (run >= NRUNS) return;
    const int lane = threadIdx.x & 63;
    const int c0 = lane * 2, c1 = c0 + 1;

    const float wea0 = We[c0], wea1 = We[H + c0], wea2 = We[2 * H + c0];
    const float web0 = We[c1], web1 = We[H + c1], web2 = We[2 * H + c1];

    const uint2 rec = csrE[(size_t)run * 64 + lane];
    const int mysrc = (int)(rec.x & 0x1FFFFu);
    const int mydst = (int)((rec.x >> 17) | ((rec.y & 3u) << 15));

    float acc0 = 0.f, acc1 = 0.f;
    bool first = true;
    int cur = __builtin_amdgcn_readlane(mydst, 0);

#pragma unroll
    for (int sub = 0; sub < 4; ++sub) {
        unsigned short rowv[16];
#pragma unroll
        for (int t = 0; t < 16; ++t) {
            const int s = __builtin_amdgcn_readlane(mysrc, sub * 16 + t);
            rowv[t] = th[(size_t)s * 64 + lane];
        }
#pragma unroll
        for (int t = 0; t < 16; ++t) {
            const int e = sub * 16 + t;
            const unsigned hi = (unsigned)__builtin_amdgcn_readlane((int)rec.y, e);
            const float e0f = fp8_dec((hi >> 2) & 0xffu);
            const float e1f = fp8_dec((hi >> 10) & 0xffu);
            const float e3f = fp8_dec((hi >> 18) & 0xffu);
            const float th0 = fp8_dec(rowv[t] & 0xffu);
            const float th1 = fp8_dec((unsigned)rowv[t] >> 8);
            const float w0 = fmaf(e0f, wea0, fmaf(e1f, wea1, e3f * wea2));
            const float w1 = fmaf(e0f, web0, fmaf(e1f, web1, e3f * web2));
            acc0 = fmaf(th0, w0, acc0);
            acc1 = fmaf(th1, w1, acc1);

            const int nxt = (e < 63) ? __builtin_amdgcn_readlane(mydst, e + 1) : -1;
            if (nxt != cur) {
                unsigned* p = agg + (size_t)cur * 64 + lane;
                if (first || e == 63) {
                    unsigned old = *p;
                    while (true) {
                        const float g0 = __uint_as_float(old << 16) + acc0;
                        const float g1 = __uint_as_float(old & 0xffff0000u) + acc1;
                        const unsigned nw = pack_bf16(g0, g1);
                        const unsigned prev = atomicCAS(p, old, nw);
                        if (prev == old) break;
                        old = prev;
                    }
                } else {
                    *p = pack_bf16(acc0, acc1);
                }
                acc0 = 0.f; acc1 = 0.f;
                first = false;
                cur = nxt;
            }
        }
    }
}

// ---------------------------------------------------------------------------
// Node kernel: wave per node, 2ch/lane. ctx via LDS reduce + per-block row.
// ---------------------------------------------------------------------------
__global__ __launch_bounds__(256) void node_kernel(
    const float* __restrict__ x, const float* __restrict__ pos,
    const unsigned* __restrict__ agg,
    const float* __restrict__ Wx, const float* __restrict__ Wp,
    const float* __restrict__ Wout,
    float* __restrict__ out_sup, float* __restrict__ ctx_part)
{
    const int lane = threadIdx.x & 63;
    const int wv   = threadIdx.x >> 6;
    const int c0 = lane * 2, c1 = c0 + 1;

    float wxa[DXI], wxb_[DXI];
#pragma unroll
    for (int k = 0; k < DXI; ++k) { wxa[k] = Wx[k * H + c0]; wxb_[k] = Wx[k * H + c1]; }
    const float wp00 = Wp[c0], wp01 = Wp[H + c0];
    const float wp10 = Wp[c1], wp11 = Wp[H + c1];
    const float woa0 = Wout[c0 * 3], woa1 = Wout[c0 * 3 + 1], woa2 = Wout[c0 * 3 + 2];
    const float wob0 = Wout[c1 * 3], wob1 = Wout[c1 * 3 + 1], wob2 = Wout[c1 * 3 + 2];

    float ctx0 = 0.f, ctx1 = 0.f;

    for (int n = blockIdx.x * 4 + wv; n < NNODES; n += gridDim.x * 4) {
        const unsigned ag = agg[(size_t)n * 64 + lane];
        const float* xr = x + (size_t)n * DXI;
        const float px = pos[(size_t)n * 3], py = pos[(size_t)n * 3 + 1];
        float a0 = fmaf(wp00, px, wp01 * py);
        float a1 = fmaf(wp10, px, wp11 * py);
#pragma unroll
        for (int k = 0; k < DXI; ++k) {
            const float xv = xr[k];
            a0 = fmaf(xv, wxa[k], a0);
            a1 = fmaf(xv, wxb_[k], a1);
        }
        const float h0 = fast_tanh(fast_tanh(a0) + __uint_as_float(ag << 16));
        const float h1 = fast_tanh(fast_tanh(a1) + __uint_as_float(ag & 0xffff0000u));
        ctx0 += h0; ctx1 += h1;

        float p0 = fmaf(h0, woa0, h1 * wob0);
        float p1 = fmaf(h0, woa1, h1 * wob1);
        float p2 = fmaf(h0, woa2, h1 * wob2);
#pragma unroll
        for (int m = 32; m; m >>= 1) {
            p0 += __shfl_xor(p0, m);
            p1 += __shfl_xor(p1, m);
            p2 += __shfl_xor(p2, m);
        }
        if (lane == 0) {
            out_sup[(size_t)n * 3 + 0] = p0;
            out_sup[(size_t)n * 3 + 1] = p1;
            out_sup[(size_t)n * 3 + 2] = p2;
        }
    }

    __shared__ float part[4][H];
    part[wv][c0] = ctx0;
    part[wv][c1] = ctx1;
    __syncthreads();
    if (threadIdx.x < H) {
        const int ch = threadIdx.x;
        ctx_part[(size_t)blockIdx.x * H + ch] =
            part[0][ch] + part[1][ch] + part[2][ch] + part[3][ch];
    }
}

// ---------------------------------------------------------------------------
// ctx finalize: sum per-block partial rows, then tab rows.
// ---------------------------------------------------------------------------
__global__ __launch_bounds__(128) void ctx_kernel(
    const float* __restrict__ ctx_part, const float* __restrict__ W1,
    const float* __restrict__ b1, float* __restrict__ tab)
{
    __shared__ float ctx[H];
    const int ch = threadIdx.x;
    float s0 = 0.f, s1 = 0.f, s2 = 0.f, s3 = 0.f;
#pragma unroll 4
    for (int b = 0; b < NODE_BLOCKS; b += 4) {
        s0 += ctx_part[(size_t)(b + 0) * H + ch];
        s1 += ctx_part[(size_t)(b + 1) * H + ch];
        s2 += ctx_part[(size_t)(b + 2) * H + ch];
        s3 += ctx_part[(size_t)(b + 3) * H + ch];
    }
    ctx[ch] = (s0 + s1 + s2 + s3) * (1.0f / (float)NNODES);
    __syncthreads();
    float acc = b1[ch];
    for (int k = 0; k < H; ++k) acc = fmaf(ctx[k], W1[(size_t)(2 + k) * H + ch], acc);
    const float A0 = W1[ch], A1 = W1[H + ch];
    tab[ch * 8 + 0] = A0;
    tab[ch * 8 + 1] = A1;
    tab[ch * 8 + 2] = acc;
    tab[ch * 8 + 3] = A0 * A0;
    tab[ch * 8 + 4] = A1 * A1;
    tab[ch * 8 + 5] = 0.f;
    tab[ch * 8 + 6] = 0.f;
    tab[ch * 8 + 7] = 0.f;
}

// ---------------------------------------------------------------------------
// Sampling kernel (MFMA): block = 32 points, 256 thr = 4 waves.
// 5 GEMMs C_q = A_q x W2 share one B (bf16 W2^T in LDS). Epilogue:
// tanh/physics in-register, shfl j-reduce, LDS cross-wave combine, direct
// out writes (incl. boundary residuals).
// ---------------------------------------------------------------------------
__global__ __launch_bounds__(256, 2) void samp_mfma_kernel(
    const float* __restrict__ dom, const float* __restrict__ bnd,
    const int* __restrict__ bidx,
    const float* __restrict__ x, const float* __restrict__ xmask,
    const float* __restrict__ tab,
    const float* __restrict__ W2, const float* __restrict__ b2,
    const float* __restrict__ W3, float* __restrict__ out)
{
    __shared__ __attribute__((aligned(16))) short Bt[128 * KPAD];     // 34816 B
    __shared__ __attribute__((aligned(16))) short Alds[5 * A_STRIDE]; // 43520 B
    __shared__ __attribute__((aligned(16))) float red[32][13];        // 1664 B

    const int tid = threadIdx.x;
    const int blk = blockIdx.x;

    // phase 0a: W2 -> Bt (transposed, bf16)
    for (int i = tid; i < H * H; i += 256) {
        const int k = i >> 7, n = i & 127;
        Bt[n * KPAD + k] = to_bf16(W2[i]);
    }

    // phase 0b: generate 5 A matrices for this block's 32 points
    for (int idx = tid; idx < 32 * 64; idx += 256) {
        const int pl = idx >> 6;
        const int k0 = (idx & 63) * 2;
        const int p  = blk * 32 + pl;
        float spx, spy;
        if (p < NDOM) { spx = dom[(size_t)p * 2];          spy = dom[(size_t)p * 2 + 1]; }
        else          { spx = bnd[(size_t)(p - NDOM) * 2]; spy = bnd[(size_t)(p - NDOM) * 2 + 1]; }
        float v[2][5];
#pragma unroll
        for (int kk = 0; kk < 2; ++kk) {
            const int k = k0 + kk;
            const float4 t4 = *(const float4*)(tab + (size_t)k * 8);
            const float A1s = tab[(size_t)k * 8 + 4];
            const float A0 = t4.x, A1 = t4.y, cc = t4.z, A0s = t4.w;
            const float a1 = fmaf(spx, A0, fmaf(spy, A1, cc));
            const float e  = __builtin_amdgcn_exp2f(a1 * 2.88539008f);
            const float h1 = fmaf(-2.f, __builtin_amdgcn_rcpf(e + 1.f), 1.f);
            const float t1 = fmaf(-h1, h1, 1.f);
            const float m2 = -2.f * h1 * t1;
            v[kk][0] = h1;
            v[kk][1] = t1 * A0;
            v[kk][2] = t1 * A1;
            v[kk][3] = m2 * A0s;
            v[kk][4] = m2 * A1s;
        }
        const int base = pl * KPAD + k0;
#pragma unroll
        for (int q = 0; q < 5; ++q)
            *(unsigned*)&Alds[q * A_STRIDE + base] = pack_bf16(v[0][q], v[1][q]);
    }
    __syncthreads();

    // phase 1: MFMA. wave = (pt, jh): 16 points x 64 j.
    const int lane = tid & 63;
    const int wv = tid >> 6;
    const int pt = wv >> 1;
    const int jh = wv & 1;
    const int ln = lane & 15;
    const int hi = lane >> 4;

    f32x4 acc[4][5];
#pragma unroll
    for (int nt = 0; nt < 4; ++nt)
#pragma unroll
        for (int q = 0; q < 5; ++q)
            acc[nt][q] = (f32x4){0.f, 0.f, 0.f, 0.f};

#pragma unroll
    for (int kc = 0; kc < 4; ++kc) {
        short8 af[5];
#pragma unroll
        for (int q = 0; q < 5; ++q)
            af[q] = *(const short8*)&Alds[q * A_STRIDE + (pt * 16 + ln) * KPAD + kc * 32 + hi * 8];
        short8 bfr[4];
#pragma unroll
        for (int nt = 0; nt < 4; ++nt)
            bfr[nt] = *(const short8*)&Bt[(jh * 64 + nt * 16 + ln) * KPAD + kc * 32 + hi * 8];
#pragma unroll
        for (int nt = 0; nt < 4; ++nt)
#pragma unroll
            for (int q = 0; q < 5; ++q)
                acc[nt][q] = __builtin_amdgcn_mfma_f32_16x16x32_bf16(af[q], bfr[nt], acc[nt][q], 0, 0, 0);
    }

    // phase 2: epilogue. lane holds (j = jh*64+nt*16+ln, 4 points via regs).
    float w30[4], w31[4], w32[4], b2j[4];
#pragma unroll
    for (int nt = 0; nt < 4; ++nt) {
        const int j = jh * 64 + nt * 16 + ln;
        w30[nt] = W3[j * 3];
        w31[nt] = W3[j * 3 + 1];
        w32[nt] = W3[j * 3 + 2];
        b2j[nt] = b2[j];
    }

    float rr[4][13];
#pragma unroll
    for (int i = 0; i < 4; ++i)
#pragma unroll
        for (int c = 0; c < 13; ++c) rr[i][c] = 0.f;

#pragma unroll
    for (int i = 0; i < 4; ++i) {
#pragma unroll
        for (int nt = 0; nt < 4; ++nt) {
            const float a2v  = acc[nt][0][i] + b2j[nt];
            const float d2xv = acc[nt][1][i];
            const float d2yv = acc[nt][2][i];
            const float exxv = acc[nt][3][i];
            const float eyyv = acc[nt][4][i];
            const float h2 = fast_tanh(a2v);
            const float t2 = fmaf(-h2, h2, 1.f);
            const float gx = t2 * d2xv;
            const float gy = t2 * d2yv;
            const float hxx = fmaf(-2.f * h2 * gx, d2xv, t2 * exxv);
            const float hyy = fmaf(-2.f * h2 * gy, d2yv, t2 * eyyv);
            rr[i][0]  = fmaf(h2, w30[nt], rr[i][0]);
            rr[i][1]  = fmaf(h2, w31[nt], rr[i][1]);
            rr[i][2]  = fmaf(h2, w32[nt], rr[i][2]);
            rr[i][3]  = fmaf(gx, w30[nt], rr[i][3]);
            rr[i][4]  = fmaf(gx, w31[nt], rr[i][4]);
            rr[i][5]  = fmaf(gx, w32[nt], rr[i][5]);
            rr[i][6]  = fmaf(gy, w30[nt], rr[i][6]);
            rr[i][7]  = fmaf(gy, w31[nt], rr[i][7]);
            rr[i][8]  = fmaf(gy, w32[nt], rr[i][8]);
            rr[i][9]  = fmaf(hxx, w30[nt], rr[i][9]);
            rr[i][10] = fmaf(hxx, w31[nt], rr[i][10]);
            rr[i][11] = fmaf(hyy, w30[nt], rr[i][11]);
            rr[i][12] = fmaf(hyy, w31[nt], rr[i][12]);
        }
    }

    // reduce over the 16 j-lanes
#pragma unroll
    for (int m = 1; m < 16; m <<= 1)
#pragma unroll
        for (int i = 0; i < 4; ++i)
#pragma unroll
            for (int c = 0; c < 13; ++c)
                rr[i][c] += __shfl_xor(rr[i][c], m);

    if (ln == 0 && jh == 0) {
#pragma unroll
        for (int i = 0; i < 4; ++i) {
            const int pl = pt * 16 + hi * 4 + i;
#pragma unroll
            for (int c = 0; c < 13; ++c) red[pl][c] = rr[i][c];
        }
    }
    __syncthreads();
    if (ln == 0 && jh == 1) {
#pragma unroll
        for (int i = 0; i < 4; ++i) {
            const int pl = pt * 16 + hi * 4 + i;
#pragma unroll
            for (int c = 0; c < 13; ++c) red[pl][c] += rr[i][c];
        }
    }
    __syncthreads();

    // phase 3: physics + writes, one thread per point
    if (tid < 32) {
        const int p = blk * 32 + tid;
        float s[13];
#pragma unroll
        for (int c = 0; c < 13; ++c) s[c] = red[tid][c];
        const float u = s[0], v = s[1], pp = s[2];
        const float ux = s[3], vx = s[4], px = s[5];
        const float uy = s[6], vy = s[7], py = s[8];
        const float uxx = s[9], vxx = s[10], uyy = s[11], vyy = s[12];
        if (p < NDOM) {
            out[CONT_OFF + p] = ux + vy;
            out[MOMX_OFF + p] = fmaf(u, ux, fmaf(v, uy, px)) - (uxx + uyy) * INV_RE;
            out[MOMY_OFF + p] = fmaf(u, vx, fmaf(v, vy, py)) - (vxx + vyy) * INV_RE;
        } else {
            const int i = p - NDOM;
            const int idx = bidx[i];
            const float* xbp = x + (size_t)idx * DXI;
            const float* mm = xmask + (size_t)idx * 6;
            const float tx = xbp[0], ty = xbp[1];
            const float nx = -ty, ny = tx;
            const float r_vt = fabsf(tx * u + ty * v - xbp[2]) * mm[1];
            const float r_vn = fabsf(nx * u + ny * v - xbp[3]) * mm[2];
            const float r_p  = fabsf(pp - xbp[4]) * mm[3];
            const float r_dv = fabsf(nx * ux + ny * vy - xbp[5]) * mm[4];
            const float r_dp = fabsf(nx * px + ny * py - xbp[6]) * mm[5];
            const float c = mm[1] + mm[2] + mm[3] + mm[4] + mm[5];
            out[BND_OFF + i] = (r_vt + r_vn + r_p + r_dv + r_dp) / c;
        }
    }
}

extern "C" void kernel_launch(void* const* d_in, const int* in_sizes, int n_in,
                              void* d_out, int out_size, void* d_ws, size_t ws_size,
                              hipStream_t stream) {
    const float* x     = (const float*)d_in[0];
    const float* xmask = (const float*)d_in[1];
    const int*   eidx  = (const int*)d_in[2];
    const float* eattr = (const float*)d_in[3];
    const float* pos   = (const float*)d_in[4];
    const float* dom   = (const float*)d_in[6];
    const float* bnd   = (const float*)d_in[7];
    const int*   bidx  = (const int*)d_in[8];
    const float* Wx    = (const float*)d_in[9];
    const float* Wp    = (const float*)d_in[10];
    const float* We    = (const float*)d_in[11];
    const float* Wout  = (const float*)d_in[12];
    const float* W1    = (const float*)d_in[13];
    const float* b1    = (const float*)d_in[14];
    const float* W2    = (const float*)d_in[15];
    const float* b2    = (const float*)d_in[16];
    const float* W3    = (const float*)d_in[17];

    float* out = (float*)d_out;

    // workspace layout (16B-aligned sections): total ~51 MB
    int*            counts8  = (int*)d_ws;                    // 8*NNODES (3.2 MB)
    int*            offsets  = counts8 + 8 * NNODES;          // NNODES + 8
    int*            cursor   = offsets + NNODES + 8;          // NNODES
    int*            bsum     = cursor + NNODES;               // 128
    uint2*          csrE     = (uint2*)(bsum + 128);          // NEDGES uint2 (8 MB)
    unsigned short* th       = (unsigned short*)(csrE + NEDGES); // NNODES*64 ushort (12.8 MB)
    unsigned*       agg      = (unsigned*)(th + (size_t)NNODES * 64); // NNODES*64 (25.6 MB)
    float*          ctx_part = (float*)(agg + (size_t)NNODES * 64);   // NODE_BLOCKS*H (512 KB)
    float*          tab      = ctx_part + (size_t)NODE_BLOCKS * H;    // H*8

    (void)hipMemsetAsync(counts8, 0, (size_t)8 * NNODES * sizeof(int), stream);

    hist_th_kernel<<<2048, 256, 0, stream>>>(eidx, x, pos, Wx, Wp, counts8, th, (uint4*)agg);
    scan1_kernel<<<NSB, 256, 0, stream>>>(counts8, offsets, bsum);
    scan2_kernel<<<1, 128, 0, stream>>>(bsum);
    scan3_kernel<<<NSB, 256, 0, stream>>>(offsets, cursor, bsum);
    scatter_kernel<<<8192, 256, 0, stream>>>(eidx, eattr, cursor, csrE);
    seg_edge_kernel<<<(NRUNS + 3) / 4, 256, 0, stream>>>(csrE, th, We, agg);
    node_kernel<<<NODE_BLOCKS, 256, 0, stream>>>(x, pos, agg, Wx, Wp, Wout, out, ctx_part);
    ctx_kernel<<<1, H, 0, stream>>>(ctx_part, W1, b1, tab);
    samp_mfma_kernel<<<NPTS / 32, 256, 0, stream>>>(dom, bnd, bidx, x, xmask, tab, W2, b2, W3, out);
}